// Round 16
// baseline (519.920 us; speedup 1.0000x reference)
//
#include <hip/hip_runtime.h>

#define EPS 1e-5f

typedef unsigned short u16;
typedef unsigned int u32;
typedef _Float16 f16;
typedef __attribute__((ext_vector_type(8))) u16 u16x8;
typedef __attribute__((ext_vector_type(2))) u32 u32x2;
typedef __attribute__((ext_vector_type(4))) u32 u32x4;
typedef __attribute__((ext_vector_type(8))) __bf16 bf16x8;
typedef __attribute__((ext_vector_type(2))) __bf16 bf16x2;
typedef __attribute__((ext_vector_type(8))) f16 f16x8;
typedef __attribute__((ext_vector_type(2))) f16 f16x2;
typedef __attribute__((ext_vector_type(4))) float f32x4;
typedef __attribute__((ext_vector_type(2))) float f32x2;

typedef __attribute__((address_space(3))) u32 lds_u32;
typedef __attribute__((address_space(1))) const u32 gbl_u32;

__device__ __forceinline__ float bf2f(u16 h) {
  return __uint_as_float(((unsigned)h) << 16);
}
__device__ __forceinline__ u32 pk2bf(float a, float b) {  // elt0 -> low 16 bits, RNE
  f32x2 v = {a, b};
  return __builtin_bit_cast(u32, __builtin_convertvector(v, bf16x2));
}
__device__ __forceinline__ u16 b2u(float f) {
  return __builtin_bit_cast(u16, (__bf16)f);
}
__device__ __forceinline__ u32 pk2h(float a, float b) {  // f16 pair, elt0 low, RNE
  f32x2 v = {a, b};
  return __builtin_bit_cast(u32, __builtin_convertvector(v, f16x2));
}
__device__ __forceinline__ float h2f(u16 u) {
  return (float)__builtin_bit_cast(f16, u);
}
__device__ __forceinline__ float ubf(u32 u) { return __uint_as_float(u); }
__device__ __forceinline__ f32x4 mfma16(u16x8 a, u16x8 b, f32x4 c) {  // bf16
  return __builtin_amdgcn_mfma_f32_16x16x32_bf16(
      __builtin_bit_cast(bf16x8, a), __builtin_bit_cast(bf16x8, b), c, 0, 0, 0);
}
__device__ __forceinline__ f32x4 mfma16h(u16x8 a, u16x8 b, f32x4 c) {  // f16
  return __builtin_amdgcn_mfma_f32_16x16x32_f16(
      __builtin_bit_cast(f16x8, a), __builtin_bit_cast(f16x8, b), c, 0, 0, 0);
}
__device__ __forceinline__ void gl16(const u16* g, u16* l) {
  __builtin_amdgcn_global_load_lds((gbl_u32*)g, (lds_u32*)l, 16, 0, 0);
}

// ps/p2 accumulation from a packed f16 pair: fdot2 when available, f32 fallback.
#if __has_builtin(__builtin_amdgcn_fdot2)
#define ACC_PS_P2(wrd, ps, p2)                                          \
  do {                                                                  \
    f16x2 _h = __builtin_bit_cast(f16x2, (u32)(wrd));                   \
    f16x2 _one = {(f16)1.0f, (f16)1.0f};                                \
    ps = __builtin_amdgcn_fdot2(_h, _one, ps, false);                   \
    p2 = __builtin_amdgcn_fdot2(_h, _h, p2, false);                     \
  } while (0)
#else
#define ACC_PS_P2(wrd, ps, p2)                                          \
  do {                                                                  \
    float _a = h2f((u16)(wrd)), _b = h2f((u16)((wrd) >> 16));           \
    ps += _a + _b;                                                      \
    p2 = fmaf(_a, _a, fmaf(_b, _b, p2));                                \
  } while (0)
#endif

// ---------------- K_init: fused W_start split bf16 (blocks 0..255) + pos table
__global__ __launch_bounds__(256) void k_init(
    const float* __restrict__ Ws, u16* __restrict__ wsh, u16* __restrict__ wsl,
    const float* __restrict__ rel_h, const float* __restrict__ rel_w,
    float* __restrict__ pos_t) {
  int bid = blockIdx.x;
  if (bid < 256) {
    int i = (bid * 256 + threadIdx.x) * 4;
    f32x4 v = *(const f32x4*)(Ws + i);
    u32 h01 = pk2bf(v[0], v[1]), h23 = pk2bf(v[2], v[3]);
    u32 l01 = pk2bf(v[0] - ubf(h01 << 16), v[1] - ubf(h01 & 0xffff0000u));
    u32 l23 = pk2bf(v[2] - ubf(h23 << 16), v[3] - ubf(h23 & 0xffff0000u));
    u32x2 hh = {h01, h23}, ll = {l01, l23};
    *(u32x2*)(wsh + i) = hh;
    *(u32x2*)(wsl + i) = ll;
  } else {
    int t = (bid - 256) * 256 + threadIdx.x;  // 524288 exact
    int d = t & 63;
    int n = (t >> 6) & 1023;
    int h = t >> 16;
    int hh = n & 31, ww = n >> 5;
    pos_t[t] = rel_h[(h * 64 + d) * 32 + hh] + rel_w[(h * 64 + d) * 32 + ww];
  }
}

// ---------------- K1: s = W_start @ x + b -> qh (single f16, n-major) + qsum partials.
__global__ __launch_bounds__(256, 2) void k_conv(
    const float* __restrict__ x, const u16* __restrict__ wsh, const u16* __restrict__ wsl,
    const float* __restrict__ bs, u16* __restrict__ qh, float* __restrict__ qpart) {
  __shared__ u16 xt_h[64 * 72], xt_l[64 * 72];
  __shared__ __align__(16) u16 wbuf[3][2][4096];  // [buf][h/l][64*64]  48KB
  const int on = blockIdx.x, b = blockIdx.y, n0 = on * 64;
  const int t = threadIdx.x, w = t >> 6, lane = t & 63, g = lane >> 4, li = lane & 15;
  const int r8 = lane >> 3, c8 = (lane & 7) ^ r8;
  f32x4 zz = {0.f, 0.f, 0.f, 0.f};
  f32x4 acc[8][4];
#pragma unroll
  for (int ob = 0; ob < 8; ++ob)
#pragma unroll
    for (int i = 0; i < 4; ++i) acc[ob][i] = zz;

#define WSTAGE(buf, ob_, c0_)                                                 \
  do {                                                                        \
    _Pragma("unroll") for (int p = 0; p < 2; ++p) {                           \
      int rq = (ob_) * 64 + 16 * w + 8 * p + r8;                              \
      gl16(wsh + (size_t)rq * 512 + (c0_) + 8 * c8,                           \
           &wbuf[buf][0][(16 * w + 8 * p) * 64]);                             \
      gl16(wsl + (size_t)rq * 512 + (c0_) + 8 * c8,                           \
           &wbuf[buf][1][(16 * w + 8 * p) * 64]);                             \
    }                                                                         \
  } while (0)

  for (int kc = 0; kc < 8; ++kc) {
    const int c0 = kc * 64;
    __syncthreads();
    int c = t >> 2, ns = (t & 3) * 16;
    const float* src = x + ((size_t)b * 512 + c0 + c) * 1024 + n0 + ns;
    f32x4 xr[4];
#pragma unroll
    for (int k = 0; k < 4; ++k) xr[k] = *(const f32x4*)(src + 4 * k);
    WSTAGE(0, 0, c0);
    WSTAGE(1, 1, c0);
#pragma unroll
    for (int k = 0; k < 4; ++k)
#pragma unroll
      for (int j = 0; j < 4; ++j) {
        float v = xr[k][j];
        u16 hv = b2u(v);
        int n = ns + 4 * k + j;
        xt_h[n * 72 + c] = hv;
        xt_l[n * 72 + c] = b2u(v - bf2f(hv));
      }
    __syncthreads();
    u16x8 bx_h[2][4], bx_l[2][4];
#pragma unroll
    for (int ks = 0; ks < 2; ++ks)
#pragma unroll
      for (int nf = 0; nf < 4; ++nf) {
        bx_h[ks][nf] = *(const u16x8*)&xt_h[(16 * nf + li) * 72 + g * 8 + 32 * ks];
        bx_l[ks][nf] = *(const u16x8*)&xt_l[(16 * nf + li) * 72 + g * 8 + 32 * ks];
      }
#pragma unroll
    for (int ob = 0; ob < 8; ++ob) {
      if (ob < 6) WSTAGE((ob + 2) % 3, ob + 2, c0);
      if (ob >= 2 && ob < 6) {
        asm volatile("s_waitcnt vmcnt(8)" ::: "memory");
      } else if (ob == 6) {
        asm volatile("s_waitcnt vmcnt(4)" ::: "memory");
      } else if (ob == 7) {
        asm volatile("s_waitcnt vmcnt(0)" ::: "memory");
      }
      const char* wb = (const char*)&wbuf[ob % 3][0][0];
      const char* wl = (const char*)&wbuf[ob % 3][1][0];
      u16x8 ah[2], al[2];
#pragma unroll
      for (int ks = 0; ks < 2; ++ks) {
        int off = (16 * w + li) * 128 + (((4 * ks + g) * 16) ^ ((li & 7) << 4));
        ah[ks] = *(const u16x8*)(wb + off);
        al[ks] = *(const u16x8*)(wl + off);
      }
#pragma unroll
      for (int ks = 0; ks < 2; ++ks)
#pragma unroll
        for (int nf = 0; nf < 4; ++nf) {
          acc[ob][nf] = mfma16(ah[ks], bx_h[ks][nf], acc[ob][nf]);
          acc[ob][nf] = mfma16(ah[ks], bx_l[ks][nf], acc[ob][nf]);
          acc[ob][nf] = mfma16(al[ks], bx_h[ks][nf], acc[ob][nf]);
        }
    }
  }
#undef WSTAGE
  // ---- epilogue: bias, q stores as single f16, qsum partials
#pragma unroll
  for (int ob = 0; ob < 8; ++ob) {
    const int o0 = ob * 64, bh = b * 8 + ob;
    float bias[4];
#pragma unroll
    for (int r = 0; r < 4; ++r) bias[r] = bs[o0 + 16 * w + g * 4 + r];
    float vq[4] = {0.f, 0.f, 0.f, 0.f};
#pragma unroll
    for (int nf = 0; nf < 4; ++nf) {
      float v0 = acc[ob][nf][0] + bias[0], v1 = acc[ob][nf][1] + bias[1];
      float v2 = acc[ob][nf][2] + bias[2], v3 = acc[ob][nf][3] + bias[3];
      vq[0] += v0; vq[1] += v1; vq[2] += v2; vq[3] += v3;
      u32 h01 = pk2h(v0, v1), h23 = pk2h(v2, v3);
      size_t base = ((size_t)bh * 1024 + n0 + 16 * nf + li) * 64 + 16 * w + g * 4;
      u32x2 ph = {h01, h23};
      *(u32x2*)(qh + base) = ph;
    }
#pragma unroll
    for (int r = 0; r < 4; ++r) {
      float s = vq[r];
      s += __shfl_xor(s, 1, 64);
      s += __shfl_xor(s, 2, 64);
      s += __shfl_xor(s, 4, 64);
      s += __shfl_xor(s, 8, 64);
      if (li == 0) qpart[((size_t)bh * 16 + on) * 64 + 16 * w + 4 * g + r] = s;
    }
  }
}

// ---------------- K_vw: Vw = W_lin @ q per (bh, n-half); q single f16, W 2-term.
__global__ __launch_bounds__(256) void k_vw(
    const u16* __restrict__ qh, const float* __restrict__ Wlin, u16* __restrict__ vw) {
  __shared__ __align__(16) u16 qbuf[2][4096];  // [buf][64n x 64d] 16KB
  __shared__ u16 lw_h[64 * 72], lw_l[64 * 72];
  __shared__ u16 bounce[64 * 72];
  const int bh = blockIdx.x >> 1, half = blockIdx.x & 1;
  const int t = threadIdx.x, w = t >> 6, lane = t & 63, g = lane >> 4, li = lane & 15;
  const int r8 = lane >> 3, c8 = (lane & 7) ^ r8;
  const u16* qhb = qh + (size_t)bh * 65536;
  f32x4 zz = {0.f, 0.f, 0.f, 0.f};

  {  // stage W_lin split (f16)
    int e = t >> 2, ds = (t & 3) * 16;
    const float* src = Wlin + e * 64 + ds;
    float arr[16];
#pragma unroll
    for (int k = 0; k < 4; ++k) *(f32x4*)&arr[4 * k] = *(const f32x4*)(src + 4 * k);
#pragma unroll
    for (int p = 0; p < 8; ++p) {
      float a = arr[2 * p], c = arr[2 * p + 1];
      u32 hw = pk2h(a, c);
      u32 lw = pk2h(a - h2f((u16)hw), c - h2f((u16)(hw >> 16)));
      *(u32*)&lw_h[e * 72 + ds + 2 * p] = hw;
      *(u32*)&lw_l[e * 72 + ds + 2 * p] = lw;
    }
  }
#define STAGE_Q(bb, n0_)                                                      \
  do {                                                                        \
    _Pragma("unroll") for (int p = 0; p < 2; ++p) {                           \
      int rq = (n0_) + 8 * (w + 4 * p) + r8;                                  \
      gl16(qhb + (size_t)rq * 64 + 8 * c8, &qbuf[bb][(8 * (w + 4 * p)) * 64]); \
    }                                                                         \
  } while (0)

  const int nt0 = half * 8;
  STAGE_Q(0, nt0 * 64);
  __syncthreads();
  u16x8 la_h[2], la_l[2];
#pragma unroll
  for (int ks = 0; ks < 2; ++ks) {
    la_h[ks] = *(const u16x8*)&lw_h[(16 * w + li) * 72 + g * 8 + 32 * ks];
    la_l[ks] = *(const u16x8*)&lw_l[(16 * w + li) * 72 + g * 8 + 32 * ks];
  }
  int cur = 0;
  for (int it = 0; it < 8; ++it) {
    const int nt = nt0 + it;
    if (it < 7) STAGE_Q(cur ^ 1, (nt + 1) * 64);
    f32x4 acc2[4] = {zz, zz, zz, zz};
    const char* qb0 = (const char*)&qbuf[cur][0];
#pragma unroll
    for (int ks = 0; ks < 2; ++ks)
#pragma unroll
      for (int nf = 0; nf < 4; ++nf) {
        int off = (16 * nf + li) * 128 + (((4 * ks + g) * 16) ^ ((li & 7) << 4));
        u16x8 qv = *(const u16x8*)(qb0 + off);
        acc2[nf] = mfma16h(la_h[ks], qv, acc2[nf]);
        acc2[nf] = mfma16h(la_l[ks], qv, acc2[nf]);
      }
    __syncthreads();
#pragma unroll
    for (int nf = 0; nf < 4; ++nf)
#pragma unroll
      for (int r = 0; r < 4; ++r)
        bounce[(16 * w + 4 * g + r) * 72 + 16 * nf + li] =
            __builtin_bit_cast(u16, (f16)acc2[nf][r]);
    __syncthreads();
    {  // coalesced Vw store: [bh][e][n]
      int e = t >> 2, nc = (t & 3) * 16;
      u16x8 v0 = *(const u16x8*)&bounce[e * 72 + nc];
      u16x8 v1 = *(const u16x8*)&bounce[e * 72 + nc + 8];
      size_t base = ((size_t)bh * 64 + e) * 1024 + nt * 64 + nc;
      *(u16x8*)(vw + base) = v0;
      *(u16x8*)(vw + base + 8) = v1;
    }
    cur ^= 1;
  }
#undef STAGE_Q
}

// ---------------- K2: flash attention; 4 j-sets/wave (JBLK=512, grid 512);
// lane-local max check (equivalent trigger), shuffles only on rescale.
__global__ __launch_bounds__(512, 4) void k_attn(
    const u16* __restrict__ qh, const u16* __restrict__ vw,
    const float* __restrict__ pos_t, float* __restrict__ pout, float* __restrict__ sump2_g) {
  __shared__ __align__(16) char smem[49184];  // kbuf 32K | ptw 8x2K | wvar 32B
  u16(*kbuf)[2][4096] = (u16(*)[2][4096])smem;  // [buf][{kh,vw}][64*64]
  float* wvar = (float*)(smem + 49152);
  const int bid = blockIdx.x, bh = bid & 255, half = bid >> 8;
  const int b = bh >> 3, h = bh & 7;
  const int t = threadIdx.x, w = t >> 6, lane = t & 63, g = lane >> 4, li = lane & 15;
  char* ptw = smem + 32768 + w * 2048;
  const u16* qhb = qh + (size_t)bh * 65536;
  const u16* vwb = vw + (size_t)bh * 65536;
  const float* posb = pos_t + (size_t)h * 65536;
  const float SIL = 0.088388347648318447f * 1.4426950408889634f;
  const float L2E = 1.4426950408889634f;
  const int swz = (li & 7) << 4;
  f32x4 zz = {0.f, 0.f, 0.f, 0.f};

  // ---- Q fragments for 4 sets (log2-scaled), single-f16 q
  u16x8 qb_h[4][2];
  const int jr0 = half * 512 + 16 * w;
#pragma unroll
  for (int s = 0; s < 4; ++s) {
    int jr = jr0 + s * 128 + li;
#pragma unroll
    for (int ks = 0; ks < 2; ++ks) {
      int dc = 32 * ks + 8 * g;
      u16x8 hh = *(const u16x8*)(qhb + (size_t)jr * 64 + dc);
      const float* sp = posb + (size_t)jr * 64 + dc;
      f32x4 p0 = *(const f32x4*)sp, p1 = *(const f32x4*)(sp + 4);
      u32 AW[4];
#pragma unroll
      for (int p = 0; p < 4; ++p) {
        float pa = (2 * p < 4) ? p0[2 * p] : p1[2 * p - 4];
        float pb = (2 * p + 1 < 4) ? p0[2 * p + 1] : p1[2 * p - 3];
        float v0 = h2f(hh[2 * p]) * SIL + pa * L2E;
        float v1 = h2f(hh[2 * p + 1]) * SIL + pb * L2E;
        AW[p] = pk2h(v0, v1);
      }
      u32x4 av = {AW[0], AW[1], AW[2], AW[3]};
      qb_h[s][ks] = __builtin_bit_cast(u16x8, av);
    }
  }

#define STAGE(bb, k0)                                                         \
  do {                                                                        \
    int r8 = lane >> 3, c8 = (lane & 7) ^ r8;                                 \
    int rq = (k0) + 8 * w + r8;                                               \
    gl16(qhb + (size_t)rq * 64 + 8 * c8, &kbuf[bb][0][w * 512]);              \
    gl16(vwb + (size_t)(8 * w + r8) * 1024 + (k0) + 8 * c8,                   \
         &kbuf[bb][1][w * 512]);                                              \
  } while (0)

  float m0 = -3.0e38f, l0 = 0.f, s20 = 0.f;
  float m1 = -3.0e38f, l1 = 0.f, s21 = 0.f;
  float m2 = -3.0e38f, l2 = 0.f, s22 = 0.f;
  float m3 = -3.0e38f, l3 = 0.f, s23 = 0.f;
  f32x4 O0[4], O1[4], O2[4], O3[4];
#pragma unroll
  for (int df = 0; df < 4; ++df) {
    O0[df] = zz;
    O1[df] = zz;
    O2[df] = zz;
    O3[df] = zz;
  }

  // Lane-local max check; full row-reduce + rescale only when triggered
  // (provably same trigger: row-max>mm+12 iff __any(lane-local max>mm+12)).
#define SOFT(S, mm, ll, ss2, O)                                               \
  do {                                                                        \
    float t0 = fmaxf(fmaxf(S[0][0], S[0][1]), fmaxf(S[0][2], S[0][3]));       \
    float t1 = fmaxf(fmaxf(S[1][0], S[1][1]), fmaxf(S[1][2], S[1][3]));       \
    float t2 = fmaxf(fmaxf(S[2][0], S[2][1]), fmaxf(S[2][2], S[2][3]));       \
    float t3 = fmaxf(fmaxf(S[3][0], S[3][1]), fmaxf(S[3][2], S[3][3]));       \
    float tl = fmaxf(fmaxf(t0, t1), fmaxf(t2, t3));                           \
    if (__any(tl > mm + 12.f)) {                                              \
      float tm = fmaxf(tl, __shfl_xor(tl, 16, 64));                           \
      tm = fmaxf(tm, __shfl_xor(tm, 32, 64));                                 \
      float mn = fmaxf(mm, tm);                                               \
      float cr = __builtin_amdgcn_exp2f(mm - mn);                             \
      mm = mn;                                                                \
      ll *= cr;                                                               \
      ss2 *= cr * cr;                                                         \
      _Pragma("unroll") for (int df = 0; df < 4; ++df) O[df] *= cr;           \
    }                                                                         \
    _Pragma("unroll") for (int nf = 0; nf < 4; ++nf) {                        \
      _Pragma("unroll") for (int r = 0; r < 4; ++r)                           \
        S[nf][r] = __builtin_amdgcn_exp2f(S[nf][r] - mm);                     \
    }                                                                         \
    float ps = 0.f, p2 = 0.f;                                                 \
    _Pragma("unroll") for (int nf = 0; nf < 4; ++nf) {                        \
      u32 w0 = pk2h(S[nf][0], S[nf][1]);                                      \
      u32 w1 = pk2h(S[nf][2], S[nf][3]);                                      \
      ACC_PS_P2(w0, ps, p2);                                                  \
      ACC_PS_P2(w1, ps, p2);                                                  \
      int slot = 2 * nf + (g >> 1);                                           \
      u32x2 pk = {w0, w1};                                                    \
      *(u32x2*)(ptw + li * 128 + ((slot * 16) ^ swz) + (g & 1) * 8) = pk;     \
    }                                                                         \
    ll += ps;                                                                 \
    ss2 += p2;                                                                \
  } while (0)

#define RD_PB(pb)                                                             \
  do {                                                                        \
    pb[0] = *(const u16x8*)(ptw + li * 128 + ((g * 16) ^ swz));               \
    pb[1] = *(const u16x8*)(ptw + li * 128 + (((4 + g) * 16) ^ swz));         \
  } while (0)

  int cur = 0;
  STAGE(0, 0);
  __syncthreads();
  for (int kc = 0; kc < 16; ++kc) {
    if (kc < 15) STAGE(cur ^ 1, (kc + 1) * 64);
    const char* kb = (const char*)&kbuf[cur][0][0];
    const char* vb = (const char*)&kbuf[cur][1][0];
    u16x8 pb0[2], pb1[2], pb2[2], pb3[2];
    {  // phase A: sets 0,1
      f32x4 S0[4] = {zz, zz, zz, zz};
      f32x4 S1[4] = {zz, zz, zz, zz};
      __builtin_amdgcn_s_setprio(1);
#pragma unroll
      for (int ks = 0; ks < 2; ++ks) {
#pragma unroll
        for (int nf = 0; nf < 4; ++nf) {
          int off = (16 * nf + li) * 128 + (((4 * ks + g) * 16) ^ swz);
          u16x8 kh = *(const u16x8*)(kb + off);
          S0[nf] = mfma16h(kh, qb_h[0][ks], S0[nf]);
          S1[nf] = mfma16h(kh, qb_h[1][ks], S1[nf]);
        }
      }
      __builtin_amdgcn_s_setprio(0);
      SOFT(S0, m0, l0, s20, O0);
      RD_PB(pb0);
      SOFT(S1, m1, l1, s21, O1);
      RD_PB(pb1);
    }
    {  // phase B: sets 2,3
      f32x4 S2[4] = {zz, zz, zz, zz};
      f32x4 S3[4] = {zz, zz, zz, zz};
      __builtin_amdgcn_s_setprio(1);
#pragma unroll
      for (int ks = 0; ks < 2; ++ks) {
#pragma unroll
        for (int nf = 0; nf < 4; ++nf) {
          int off = (16 * nf + li) * 128 + (((4 * ks + g) * 16) ^ swz);
          u16x8 kh = *(const u16x8*)(kb + off);
          S2[nf] = mfma16h(kh, qb_h[2][ks], S2[nf]);
          S3[nf] = mfma16h(kh, qb_h[3][ks], S3[nf]);
        }
      }
      __builtin_amdgcn_s_setprio(0);
      SOFT(S2, m2, l2, s22, O2);
      RD_PB(pb2);
      SOFT(S3, m3, l3, s23, O3);
      RD_PB(pb3);
    }
    __builtin_amdgcn_s_setprio(1);
#pragma unroll
    for (int ks = 0; ks < 2; ++ks) {
#pragma unroll
      for (int df = 0; df < 4; ++df) {
        u16x8 va = *(const u16x8*)(vb + (16 * df + li) * 128 + (((4 * ks + g) * 16) ^ swz));
        O0[df] = mfma16h(va, pb0[ks], O0[df]);
        O1[df] = mfma16h(va, pb1[ks], O1[df]);
        O2[df] = mfma16h(va, pb2[ks], O2[df]);
        O3[df] = mfma16h(va, pb3[ks], O3[df]);
      }
    }
    __builtin_amdgcn_s_setprio(0);
    __syncthreads();
    cur ^= 1;
  }

  // ---- finalize 4 sets
  float wacc = 0.f;
#define FIN(ll, ss2, O)                                                       \
  do {                                                                        \
    ll += __shfl_xor(ll, 16, 64);                                             \
    ll += __shfl_xor(ll, 32, 64);                                             \
    ss2 += __shfl_xor(ss2, 16, 64);                                           \
    ss2 += __shfl_xor(ss2, 32, 64);                                           \
    float il = 1.0f / ll;                                                     \
    _Pragma("unroll") for (int df = 0; df < 4; ++df) O[df] *= il;             \
    float s2w = ss2 * il * il;                                                \
    s2w += __shfl_xor(s2w, 1, 64);                                            \
    s2w += __shfl_xor(s2w, 2, 64);                                            \
    s2w += __shfl_xor(s2w, 4, 64);                                            \
    s2w += __shfl_xor(s2w, 8, 64);                                            \
    wacc += s2w;                                                              \
  } while (0)
  FIN(l0, s20, O0);
  FIN(l1, s21, O1);
  FIN(l2, s22, O2);
  FIN(l3, s23, O3);
#undef FIN
  if (lane == 0) wvar[w] = wacc;

  float* bounce = (float*)smem;  // [64 e][132] f32 = 33792B
#pragma unroll
  for (int s = 0; s < 4; ++s) {
    const int jg0 = half * 512 + s * 128;
    const f32x4* Os = (s == 0) ? O0 : (s == 1) ? O1 : (s == 2) ? O2 : O3;
    __syncthreads();
#pragma unroll
    for (int df = 0; df < 4; ++df)
#pragma unroll
      for (int r = 0; r < 4; ++r)
        bounce[(df * 16 + g * 4 + r) * 132 + 16 * w + li] = Os[df][r];
    __syncthreads();
#pragma unroll
    for (int p = 0; p < 4; ++p) {
      int idx = p * 512 + t;
      int e = idx >> 5, ch = idx & 31;
      f32x4 v = *(const f32x4*)&bounce[e * 132 + ch * 4];
      *(f32x4*)&pout[((size_t)b * 512 + h * 64 + e) * 1024 + jg0 + ch * 4] = v;
    }
  }
  __syncthreads();
  if (t == 0) {
    float s = 0.f;
#pragma unroll
    for (int i = 0; i < 8; ++i) s += wvar[i];
    sump2_g[bid] = s;
  }
#undef STAGE
#undef SOFT
#undef RD_PB
}

// ---------------- K3a: per-bh constants
__global__ __launch_bounds__(64) void k_cvec(
    const float* __restrict__ qpart, const float* __restrict__ sump2_g,
    const float* __restrict__ Wlin, const float* __restrict__ blin,
    float* __restrict__ cvec_g, float* __restrict__ isv_g) {
  const int bh = blockIdx.x, t = threadIdx.x;
  __shared__ float qs[64];
  float s = 0.f;
#pragma unroll
  for (int on = 0; on < 16; ++on) s += qpart[(size_t)bh * 1024 + on * 64 + t];
  qs[t] = s;
  __syncthreads();
  const float MU = 1.0f / 1024.0f;
  float sp2 = sump2_g[bh] + sump2_g[bh + 256];
  float var = sp2 * (1.0f / 1048576.0f) - MU * MU;
  float isv = 1.0f / sqrtf(var + EPS);
  float wq = 0.f;
  for (int d = 0; d < 64; ++d) wq += Wlin[t * 64 + d] * qs[d];
  cvec_g[bh * 64 + t] = blin[t] - isv * MU * wq;
  if (t == 0) isv_g[bh] = isv;
}

// ---------------- K3b: out = isv * P_out + cvec[e] + x
__global__ __launch_bounds__(256) void k_fin(
    float* __restrict__ out, const float* __restrict__ x,
    const float* __restrict__ cvec_g, const float* __restrict__ isv_g) {
  const int bid = blockIdx.x, t = threadIdx.x;
  const int bh = bid >> 3, part = bid & 7;
  const float isv = isv_g[bh];
  const size_t base = (size_t)bh * 65536 + part * 8192;
#pragma unroll
  for (int it = 0; it < 8; ++it) {
    size_t off = base + it * 1024 + t * 4;
    float cv = cvec_g[bh * 64 + part * 8 + it];
    f32x4 po = *(const f32x4*)(out + off);
    f32x4 xv = *(const f32x4*)(x + off);
    f32x4 res;
#pragma unroll
    for (int k = 0; k < 4; ++k) res[k] = isv * po[k] + cv + xv[k];
    *(f32x4*)(out + off) = res;
  }
}

extern "C" void kernel_launch(void* const* d_in, const int* in_sizes, int n_in,
                              void* d_out, int out_size, void* d_ws, size_t ws_size,
                              hipStream_t stream) {
  const float* x = (const float*)d_in[0];
  const float* Ws = (const float*)d_in[1];
  const float* bs = (const float*)d_in[2];
  const float* rh = (const float*)d_in[3];
  const float* rw = (const float*)d_in[4];
  const float* Wl = (const float*)d_in[5];
  const float* bl = (const float*)d_in[6];
  char* wsb = (char*)d_ws;
  u16* qh = (u16*)wsb;                               // 32 MiB  q f16, n-major [bh][n][d]
  u16* vw = (u16*)(wsb + (size_t)67108864);          // 32 MiB  Vw f16, d-major [bh][e][n]
  float* pos_t = (float*)(wsb + (size_t)100663296);  //  2 MiB  pos [h][n][d]
  float* qpart = (float*)(wsb + (size_t)102760448);  //  1 MiB  qsum partials
  float* s2g = (float*)(wsb + (size_t)103809024);    //  4 KiB
  float* cvec = (float*)(wsb + (size_t)103813120);   // 64 KiB
  float* isvg = (float*)(wsb + (size_t)103878656);   //  1 KiB
  u16* wsh = (u16*)(wsb + (size_t)103880704);        // 512 KiB W_start bf16 hi
  u16* wsl = (u16*)(wsb + (size_t)104404992);        // 512 KiB W_start bf16 lo
  float* out = (float*)d_out;

  k_init<<<2304, 256, 0, stream>>>(Ws, wsh, wsl, rh, rw, pos_t);
  k_conv<<<dim3(16, 32), 256, 0, stream>>>(x, wsh, wsl, bs, qh, qpart);
  k_vw<<<512, 256, 0, stream>>>(qh, Wl, vw);
  k_attn<<<512, 512, 0, stream>>>(qh, vw, pos_t, out, s2g);
  k_cvec<<<256, 64, 0, stream>>>(qpart, s2g, Wl, bl, cvec, isvg);
  k_fin<<<2048, 256, 0, stream>>>(out, x, cvec, isvg);
}

// Round 17
// 242.204 us; speedup vs baseline: 2.1466x; 2.1466x over previous
//
#include <hip/hip_runtime.h>

#define EPS 1e-5f

typedef unsigned short u16;
typedef unsigned int u32;
typedef _Float16 f16;
typedef __attribute__((ext_vector_type(8))) u16 u16x8;
typedef __attribute__((ext_vector_type(2))) u32 u32x2;
typedef __attribute__((ext_vector_type(4))) u32 u32x4;
typedef __attribute__((ext_vector_type(8))) __bf16 bf16x8;
typedef __attribute__((ext_vector_type(2))) __bf16 bf16x2;
typedef __attribute__((ext_vector_type(8))) f16 f16x8;
typedef __attribute__((ext_vector_type(2))) f16 f16x2;
typedef __attribute__((ext_vector_type(4))) float f32x4;
typedef __attribute__((ext_vector_type(2))) float f32x2;

typedef __attribute__((address_space(3))) u32 lds_u32;
typedef __attribute__((address_space(1))) const u32 gbl_u32;

__device__ __forceinline__ float bf2f(u16 h) {
  return __uint_as_float(((unsigned)h) << 16);
}
__device__ __forceinline__ u32 pk2bf(float a, float b) {  // elt0 -> low 16 bits, RNE
  f32x2 v = {a, b};
  return __builtin_bit_cast(u32, __builtin_convertvector(v, bf16x2));
}
__device__ __forceinline__ u16 b2u(float f) {
  return __builtin_bit_cast(u16, (__bf16)f);
}
__device__ __forceinline__ u32 pk2h(float a, float b) {  // f16 pair, elt0 low, RNE
  f32x2 v = {a, b};
  return __builtin_bit_cast(u32, __builtin_convertvector(v, f16x2));
}
__device__ __forceinline__ float h2f(u16 u) {
  return (float)__builtin_bit_cast(f16, u);
}
__device__ __forceinline__ float ubf(u32 u) { return __uint_as_float(u); }
__device__ __forceinline__ f32x4 mfma16(u16x8 a, u16x8 b, f32x4 c) {  // bf16
  return __builtin_amdgcn_mfma_f32_16x16x32_bf16(
      __builtin_bit_cast(bf16x8, a), __builtin_bit_cast(bf16x8, b), c, 0, 0, 0);
}
__device__ __forceinline__ f32x4 mfma16h(u16x8 a, u16x8 b, f32x4 c) {  // f16
  return __builtin_amdgcn_mfma_f32_16x16x32_f16(
      __builtin_bit_cast(f16x8, a), __builtin_bit_cast(f16x8, b), c, 0, 0, 0);
}
__device__ __forceinline__ void gl16(const u16* g, u16* l) {
  __builtin_amdgcn_global_load_lds((gbl_u32*)g, (lds_u32*)l, 16, 0, 0);
}

// ps/p2 accumulation from a packed f16 pair: fdot2 when available, f32 fallback.
#if __has_builtin(__builtin_amdgcn_fdot2)
#define ACC_PS_P2(wrd, ps, p2)                                          \
  do {                                                                  \
    f16x2 _h = __builtin_bit_cast(f16x2, (u32)(wrd));                   \
    f16x2 _one = {(f16)1.0f, (f16)1.0f};                                \
    ps = __builtin_amdgcn_fdot2(_h, _one, ps, false);                   \
    p2 = __builtin_amdgcn_fdot2(_h, _h, p2, false);                     \
  } while (0)
#else
#define ACC_PS_P2(wrd, ps, p2)                                          \
  do {                                                                  \
    float _a = h2f((u16)(wrd)), _b = h2f((u16)((wrd) >> 16));           \
    ps += _a + _b;                                                      \
    p2 = fmaf(_a, _a, fmaf(_b, _b, p2));                                \
  } while (0)
#endif

// ---------------- K_init: fused W_start split bf16 (blocks 0..255) + pos table
__global__ __launch_bounds__(256) void k_init(
    const float* __restrict__ Ws, u16* __restrict__ wsh, u16* __restrict__ wsl,
    const float* __restrict__ rel_h, const float* __restrict__ rel_w,
    float* __restrict__ pos_t) {
  int bid = blockIdx.x;
  if (bid < 256) {
    int i = (bid * 256 + threadIdx.x) * 4;
    f32x4 v = *(const f32x4*)(Ws + i);
    u32 h01 = pk2bf(v[0], v[1]), h23 = pk2bf(v[2], v[3]);
    u32 l01 = pk2bf(v[0] - ubf(h01 << 16), v[1] - ubf(h01 & 0xffff0000u));
    u32 l23 = pk2bf(v[2] - ubf(h23 << 16), v[3] - ubf(h23 & 0xffff0000u));
    u32x2 hh = {h01, h23}, ll = {l01, l23};
    *(u32x2*)(wsh + i) = hh;
    *(u32x2*)(wsl + i) = ll;
  } else {
    int t = (bid - 256) * 256 + threadIdx.x;  // 524288 exact
    int d = t & 63;
    int n = (t >> 6) & 1023;
    int h = t >> 16;
    int hh = n & 31, ww = n >> 5;
    pos_t[t] = rel_h[(h * 64 + d) * 32 + hh] + rel_w[(h * 64 + d) * 32 + ww];
  }
}

// ---------------- K1: s = W_start @ x + b -> qh (single f16, n-major) + qsum partials.
__global__ __launch_bounds__(256, 2) void k_conv(
    const float* __restrict__ x, const u16* __restrict__ wsh, const u16* __restrict__ wsl,
    const float* __restrict__ bs, u16* __restrict__ qh, float* __restrict__ qpart) {
  __shared__ u16 xt_h[64 * 72], xt_l[64 * 72];
  __shared__ __align__(16) u16 wbuf[3][2][4096];  // [buf][h/l][64*64]  48KB
  const int on = blockIdx.x, b = blockIdx.y, n0 = on * 64;
  const int t = threadIdx.x, w = t >> 6, lane = t & 63, g = lane >> 4, li = lane & 15;
  const int r8 = lane >> 3, c8 = (lane & 7) ^ r8;
  f32x4 zz = {0.f, 0.f, 0.f, 0.f};
  f32x4 acc[8][4];
#pragma unroll
  for (int ob = 0; ob < 8; ++ob)
#pragma unroll
    for (int i = 0; i < 4; ++i) acc[ob][i] = zz;

#define WSTAGE(buf, ob_, c0_)                                                 \
  do {                                                                        \
    _Pragma("unroll") for (int p = 0; p < 2; ++p) {                           \
      int rq = (ob_) * 64 + 16 * w + 8 * p + r8;                              \
      gl16(wsh + (size_t)rq * 512 + (c0_) + 8 * c8,                           \
           &wbuf[buf][0][(16 * w + 8 * p) * 64]);                             \
      gl16(wsl + (size_t)rq * 512 + (c0_) + 8 * c8,                           \
           &wbuf[buf][1][(16 * w + 8 * p) * 64]);                             \
    }                                                                         \
  } while (0)

  for (int kc = 0; kc < 8; ++kc) {
    const int c0 = kc * 64;
    __syncthreads();
    int c = t >> 2, ns = (t & 3) * 16;
    const float* src = x + ((size_t)b * 512 + c0 + c) * 1024 + n0 + ns;
    f32x4 xr[4];
#pragma unroll
    for (int k = 0; k < 4; ++k) xr[k] = *(const f32x4*)(src + 4 * k);
    WSTAGE(0, 0, c0);
    WSTAGE(1, 1, c0);
#pragma unroll
    for (int k = 0; k < 4; ++k)
#pragma unroll
      for (int j = 0; j < 4; ++j) {
        float v = xr[k][j];
        u16 hv = b2u(v);
        int n = ns + 4 * k + j;
        xt_h[n * 72 + c] = hv;
        xt_l[n * 72 + c] = b2u(v - bf2f(hv));
      }
    __syncthreads();
    u16x8 bx_h[2][4], bx_l[2][4];
#pragma unroll
    for (int ks = 0; ks < 2; ++ks)
#pragma unroll
      for (int nf = 0; nf < 4; ++nf) {
        bx_h[ks][nf] = *(const u16x8*)&xt_h[(16 * nf + li) * 72 + g * 8 + 32 * ks];
        bx_l[ks][nf] = *(const u16x8*)&xt_l[(16 * nf + li) * 72 + g * 8 + 32 * ks];
      }
#pragma unroll
    for (int ob = 0; ob < 8; ++ob) {
      if (ob < 6) WSTAGE((ob + 2) % 3, ob + 2, c0);
      if (ob >= 2 && ob < 6) {
        asm volatile("s_waitcnt vmcnt(8)" ::: "memory");
      } else if (ob == 6) {
        asm volatile("s_waitcnt vmcnt(4)" ::: "memory");
      } else if (ob == 7) {
        asm volatile("s_waitcnt vmcnt(0)" ::: "memory");
      }
      const char* wb = (const char*)&wbuf[ob % 3][0][0];
      const char* wl = (const char*)&wbuf[ob % 3][1][0];
      u16x8 ah[2], al[2];
#pragma unroll
      for (int ks = 0; ks < 2; ++ks) {
        int off = (16 * w + li) * 128 + (((4 * ks + g) * 16) ^ ((li & 7) << 4));
        ah[ks] = *(const u16x8*)(wb + off);
        al[ks] = *(const u16x8*)(wl + off);
      }
#pragma unroll
      for (int ks = 0; ks < 2; ++ks)
#pragma unroll
        for (int nf = 0; nf < 4; ++nf) {
          acc[ob][nf] = mfma16(ah[ks], bx_h[ks][nf], acc[ob][nf]);
          acc[ob][nf] = mfma16(ah[ks], bx_l[ks][nf], acc[ob][nf]);
          acc[ob][nf] = mfma16(al[ks], bx_h[ks][nf], acc[ob][nf]);
        }
    }
  }
#undef WSTAGE
  // ---- epilogue: bias, q stores as single f16, qsum partials
#pragma unroll
  for (int ob = 0; ob < 8; ++ob) {
    const int o0 = ob * 64, bh = b * 8 + ob;
    float bias[4];
#pragma unroll
    for (int r = 0; r < 4; ++r) bias[r] = bs[o0 + 16 * w + g * 4 + r];
    float vq[4] = {0.f, 0.f, 0.f, 0.f};
#pragma unroll
    for (int nf = 0; nf < 4; ++nf) {
      float v0 = acc[ob][nf][0] + bias[0], v1 = acc[ob][nf][1] + bias[1];
      float v2 = acc[ob][nf][2] + bias[2], v3 = acc[ob][nf][3] + bias[3];
      vq[0] += v0; vq[1] += v1; vq[2] += v2; vq[3] += v3;
      u32 h01 = pk2h(v0, v1), h23 = pk2h(v2, v3);
      size_t base = ((size_t)bh * 1024 + n0 + 16 * nf + li) * 64 + 16 * w + g * 4;
      u32x2 ph = {h01, h23};
      *(u32x2*)(qh + base) = ph;
    }
#pragma unroll
    for (int r = 0; r < 4; ++r) {
      float s = vq[r];
      s += __shfl_xor(s, 1, 64);
      s += __shfl_xor(s, 2, 64);
      s += __shfl_xor(s, 4, 64);
      s += __shfl_xor(s, 8, 64);
      if (li == 0) qpart[((size_t)bh * 16 + on) * 64 + 16 * w + 4 * g + r] = s;
    }
  }
}

// ---------------- K_vw: Vw = W_lin @ q per (bh, n-half); q single f16, W 2-term.
__global__ __launch_bounds__(256) void k_vw(
    const u16* __restrict__ qh, const float* __restrict__ Wlin, u16* __restrict__ vw) {
  __shared__ __align__(16) u16 qbuf[2][4096];  // [buf][64n x 64d] 16KB
  __shared__ u16 lw_h[64 * 72], lw_l[64 * 72];
  __shared__ u16 bounce[64 * 72];
  const int bh = blockIdx.x >> 1, half = blockIdx.x & 1;
  const int t = threadIdx.x, w = t >> 6, lane = t & 63, g = lane >> 4, li = lane & 15;
  const int r8 = lane >> 3, c8 = (lane & 7) ^ r8;
  const u16* qhb = qh + (size_t)bh * 65536;
  f32x4 zz = {0.f, 0.f, 0.f, 0.f};

  {  // stage W_lin split (f16)
    int e = t >> 2, ds = (t & 3) * 16;
    const float* src = Wlin + e * 64 + ds;
    float arr[16];
#pragma unroll
    for (int k = 0; k < 4; ++k) *(f32x4*)&arr[4 * k] = *(const f32x4*)(src + 4 * k);
#pragma unroll
    for (int p = 0; p < 8; ++p) {
      float a = arr[2 * p], c = arr[2 * p + 1];
      u32 hw = pk2h(a, c);
      u32 lw = pk2h(a - h2f((u16)hw), c - h2f((u16)(hw >> 16)));
      *(u32*)&lw_h[e * 72 + ds + 2 * p] = hw;
      *(u32*)&lw_l[e * 72 + ds + 2 * p] = lw;
    }
  }
#define STAGE_Q(bb, n0_)                                                      \
  do {                                                                        \
    _Pragma("unroll") for (int p = 0; p < 2; ++p) {                           \
      int rq = (n0_) + 8 * (w + 4 * p) + r8;                                  \
      gl16(qhb + (size_t)rq * 64 + 8 * c8, &qbuf[bb][(8 * (w + 4 * p)) * 64]); \
    }                                                                         \
  } while (0)

  const int nt0 = half * 8;
  STAGE_Q(0, nt0 * 64);
  __syncthreads();
  u16x8 la_h[2], la_l[2];
#pragma unroll
  for (int ks = 0; ks < 2; ++ks) {
    la_h[ks] = *(const u16x8*)&lw_h[(16 * w + li) * 72 + g * 8 + 32 * ks];
    la_l[ks] = *(const u16x8*)&lw_l[(16 * w + li) * 72 + g * 8 + 32 * ks];
  }
  int cur = 0;
  for (int it = 0; it < 8; ++it) {
    const int nt = nt0 + it;
    if (it < 7) STAGE_Q(cur ^ 1, (nt + 1) * 64);
    f32x4 acc2[4] = {zz, zz, zz, zz};
    const char* qb0 = (const char*)&qbuf[cur][0];
#pragma unroll
    for (int ks = 0; ks < 2; ++ks)
#pragma unroll
      for (int nf = 0; nf < 4; ++nf) {
        int off = (16 * nf + li) * 128 + (((4 * ks + g) * 16) ^ ((li & 7) << 4));
        u16x8 qv = *(const u16x8*)(qb0 + off);
        acc2[nf] = mfma16h(la_h[ks], qv, acc2[nf]);
        acc2[nf] = mfma16h(la_l[ks], qv, acc2[nf]);
      }
    __syncthreads();
#pragma unroll
    for (int nf = 0; nf < 4; ++nf)
#pragma unroll
      for (int r = 0; r < 4; ++r)
        bounce[(16 * w + 4 * g + r) * 72 + 16 * nf + li] =
            __builtin_bit_cast(u16, (f16)acc2[nf][r]);
    __syncthreads();
    {  // coalesced Vw store: [bh][e][n]
      int e = t >> 2, nc = (t & 3) * 16;
      u16x8 v0 = *(const u16x8*)&bounce[e * 72 + nc];
      u16x8 v1 = *(const u16x8*)&bounce[e * 72 + nc + 8];
      size_t base = ((size_t)bh * 64 + e) * 1024 + nt * 64 + nc;
      *(u16x8*)(vw + base) = v0;
      *(u16x8*)(vw + base + 8) = v1;
    }
    cur ^= 1;
  }
#undef STAGE_Q
}

// ---------------- K2: flash attention; 2 j-sets/wave (R15 tiling); lane-local max
// check (equivalent trigger), row-reduce shuffles only inside the rescale path.
__global__ __launch_bounds__(512, 4) void k_attn(
    const u16* __restrict__ qh, const u16* __restrict__ vw,
    const float* __restrict__ pos_t, float* __restrict__ pout, float* __restrict__ sump2_g) {
  __shared__ __align__(16) char smem[49184];  // kbuf 32K | ptw 8x2K | wvar 32B
  u16(*kbuf)[2][4096] = (u16(*)[2][4096])smem;  // [buf][{kh,vw}][64*64]
  float* wvar = (float*)(smem + 49152);
  const int bid = blockIdx.x, bh = bid & 255, quarter = bid >> 8;
  const int b = bh >> 3, h = bh & 7;
  const int t = threadIdx.x, w = t >> 6, lane = t & 63, g = lane >> 4, li = lane & 15;
  char* ptw = smem + 32768 + w * 2048;
  const u16* qhb = qh + (size_t)bh * 65536;
  const u16* vwb = vw + (size_t)bh * 65536;
  const float* posb = pos_t + (size_t)h * 65536;
  const float SIL = 0.088388347648318447f * 1.4426950408889634f;
  const float L2E = 1.4426950408889634f;
  const int swz = (li & 7) << 4;
  f32x4 zz = {0.f, 0.f, 0.f, 0.f};

  // ---- Q fragments (log2-scaled), single-f16 q
  u16x8 qb_h[2][2];
  const int jr0 = quarter * 256 + 16 * w;
#pragma unroll
  for (int s = 0; s < 2; ++s) {
    int jr = jr0 + s * 128 + li;
#pragma unroll
    for (int ks = 0; ks < 2; ++ks) {
      int dc = 32 * ks + 8 * g;
      u16x8 hh = *(const u16x8*)(qhb + (size_t)jr * 64 + dc);
      const float* sp = posb + (size_t)jr * 64 + dc;
      f32x4 p0 = *(const f32x4*)sp, p1 = *(const f32x4*)(sp + 4);
      u32 AW[4];
#pragma unroll
      for (int p = 0; p < 4; ++p) {
        float pa = (2 * p < 4) ? p0[2 * p] : p1[2 * p - 4];
        float pb = (2 * p + 1 < 4) ? p0[2 * p + 1] : p1[2 * p - 3];
        float v0 = h2f(hh[2 * p]) * SIL + pa * L2E;
        float v1 = h2f(hh[2 * p + 1]) * SIL + pb * L2E;
        AW[p] = pk2h(v0, v1);
      }
      u32x4 av = {AW[0], AW[1], AW[2], AW[3]};
      qb_h[s][ks] = __builtin_bit_cast(u16x8, av);
    }
  }

#define STAGE(bb, k0)                                                         \
  do {                                                                        \
    int r8 = lane >> 3, c8 = (lane & 7) ^ r8;                                 \
    int rq = (k0) + 8 * w + r8;                                               \
    gl16(qhb + (size_t)rq * 64 + 8 * c8, &kbuf[bb][0][w * 512]);              \
    gl16(vwb + (size_t)(8 * w + r8) * 1024 + (k0) + 8 * c8,                   \
         &kbuf[bb][1][w * 512]);                                              \
  } while (0)

  float m0 = -3.0e38f, l0 = 0.f, s20 = 0.f;
  float m1 = -3.0e38f, l1 = 0.f, s21 = 0.f;
  f32x4 O0[4], O1[4];
#pragma unroll
  for (int df = 0; df < 4; ++df) {
    O0[df] = zz;
    O1[df] = zz;
  }

  // Lane-local max check (row-max>mm+12 iff __any(lane-local max>mm+12));
  // full row-reduce + rescale only in the trigger path.
#define SOFT(S, mm, ll, ss2, O)                                               \
  do {                                                                        \
    float t0 = fmaxf(fmaxf(S[0][0], S[0][1]), fmaxf(S[0][2], S[0][3]));       \
    float t1 = fmaxf(fmaxf(S[1][0], S[1][1]), fmaxf(S[1][2], S[1][3]));       \
    float t2 = fmaxf(fmaxf(S[2][0], S[2][1]), fmaxf(S[2][2], S[2][3]));       \
    float t3 = fmaxf(fmaxf(S[3][0], S[3][1]), fmaxf(S[3][2], S[3][3]));       \
    float tl = fmaxf(fmaxf(t0, t1), fmaxf(t2, t3));                           \
    if (__any(tl > mm + 12.f)) {                                              \
      float tm = fmaxf(tl, __shfl_xor(tl, 16, 64));                           \
      tm = fmaxf(tm, __shfl_xor(tm, 32, 64));                                 \
      float mn = fmaxf(mm, tm);                                               \
      float cr = __builtin_amdgcn_exp2f(mm - mn);                             \
      mm = mn;                                                                \
      ll *= cr;                                                               \
      ss2 *= cr * cr;                                                         \
      _Pragma("unroll") for (int df = 0; df < 4; ++df) O[df] *= cr;           \
    }                                                                         \
    _Pragma("unroll") for (int nf = 0; nf < 4; ++nf) {                        \
      _Pragma("unroll") for (int r = 0; r < 4; ++r)                           \
        S[nf][r] = __builtin_amdgcn_exp2f(S[nf][r] - mm);                     \
    }                                                                         \
    float ps = 0.f, p2 = 0.f;                                                 \
    _Pragma("unroll") for (int nf = 0; nf < 4; ++nf) {                        \
      u32 w0 = pk2h(S[nf][0], S[nf][1]);                                      \
      u32 w1 = pk2h(S[nf][2], S[nf][3]);                                      \
      ACC_PS_P2(w0, ps, p2);                                                  \
      ACC_PS_P2(w1, ps, p2);                                                  \
      int slot = 2 * nf + (g >> 1);                                           \
      u32x2 pk = {w0, w1};                                                    \
      *(u32x2*)(ptw + li * 128 + ((slot * 16) ^ swz) + (g & 1) * 8) = pk;     \
    }                                                                         \
    ll += ps;                                                                 \
    ss2 += p2;                                                                \
  } while (0)

  int cur = 0;
  STAGE(0, 0);
  __syncthreads();
  for (int kc = 0; kc < 16; ++kc) {
    if (kc < 15) STAGE(cur ^ 1, (kc + 1) * 64);
    const char* kb = (const char*)&kbuf[cur][0][0];
    const char* vb = (const char*)&kbuf[cur][1][0];
    f32x4 S0[4] = {zz, zz, zz, zz};
    f32x4 S1[4] = {zz, zz, zz, zz};
    __builtin_amdgcn_s_setprio(1);
#pragma unroll
    for (int ks = 0; ks < 2; ++ks) {
#pragma unroll
      for (int nf = 0; nf < 4; ++nf) {
        int off = (16 * nf + li) * 128 + (((4 * ks + g) * 16) ^ swz);
        u16x8 kh = *(const u16x8*)(kb + off);
        S0[nf] = mfma16h(kh, qb_h[0][ks], S0[nf]);
        S1[nf] = mfma16h(kh, qb_h[1][ks], S1[nf]);
      }
    }
    __builtin_amdgcn_s_setprio(0);
    SOFT(S0, m0, l0, s20, O0);
    u16x8 pb0[2];
    pb0[0] = *(const u16x8*)(ptw + li * 128 + ((g * 16) ^ swz));
    pb0[1] = *(const u16x8*)(ptw + li * 128 + (((4 + g) * 16) ^ swz));
    SOFT(S1, m1, l1, s21, O1);
    u16x8 pb1[2];
    pb1[0] = *(const u16x8*)(ptw + li * 128 + ((g * 16) ^ swz));
    pb1[1] = *(const u16x8*)(ptw + li * 128 + (((4 + g) * 16) ^ swz));
    __builtin_amdgcn_s_setprio(1);
#pragma unroll
    for (int ks = 0; ks < 2; ++ks) {
#pragma unroll
      for (int df = 0; df < 4; ++df) {
        u16x8 va = *(const u16x8*)(vb + (16 * df + li) * 128 + (((4 * ks + g) * 16) ^ swz));
        O0[df] = mfma16h(va, pb0[ks], O0[df]);
        O1[df] = mfma16h(va, pb1[ks], O1[df]);
      }
    }
    __builtin_amdgcn_s_setprio(0);
    __syncthreads();
    cur ^= 1;
  }

  float wacc = 0.f;
  l0 += __shfl_xor(l0, 16, 64);
  l0 += __shfl_xor(l0, 32, 64);
  s20 += __shfl_xor(s20, 16, 64);
  s20 += __shfl_xor(s20, 32, 64);
  l1 += __shfl_xor(l1, 16, 64);
  l1 += __shfl_xor(l1, 32, 64);
  s21 += __shfl_xor(s21, 16, 64);
  s21 += __shfl_xor(s21, 32, 64);
  float il0 = 1.0f / l0, il1 = 1.0f / l1;
#pragma unroll
  for (int df = 0; df < 4; ++df) {
    O0[df] *= il0;
    O1[df] *= il1;
  }
  {
    float s2w = s20 * il0 * il0;
    s2w += __shfl_xor(s2w, 1, 64);
    s2w += __shfl_xor(s2w, 2, 64);
    s2w += __shfl_xor(s2w, 4, 64);
    s2w += __shfl_xor(s2w, 8, 64);
    wacc += s2w;
    float s2w1 = s21 * il1 * il1;
    s2w1 += __shfl_xor(s2w1, 1, 64);
    s2w1 += __shfl_xor(s2w1, 2, 64);
    s2w1 += __shfl_xor(s2w1, 4, 64);
    s2w1 += __shfl_xor(s2w1, 8, 64);
    wacc += s2w1;
  }
  if (lane == 0) wvar[w] = wacc;

  float* bounce = (float*)smem;  // [64 e][132] f32 = 33792B
#pragma unroll
  for (int s = 0; s < 2; ++s) {
    const int jg0 = quarter * 256 + s * 128;
    __syncthreads();
#pragma unroll
    for (int df = 0; df < 4; ++df)
#pragma unroll
      for (int r = 0; r < 4; ++r)
        bounce[(df * 16 + g * 4 + r) * 132 + 16 * w + li] = s ? O1[df][r] : O0[df][r];
    __syncthreads();
#pragma unroll
    for (int p = 0; p < 4; ++p) {
      int idx = p * 512 + t;
      int e = idx >> 5, ch = idx & 31;
      f32x4 v = *(const f32x4*)&bounce[e * 132 + ch * 4];
      *(f32x4*)&pout[((size_t)b * 512 + h * 64 + e) * 1024 + jg0 + ch * 4] = v;
    }
  }
  __syncthreads();
  if (t == 0) {
    float s = 0.f;
#pragma unroll
    for (int i = 0; i < 8; ++i) s += wvar[i];
    sump2_g[bid] = s;
  }
#undef STAGE
#undef SOFT
}

// ---------------- K3a: per-bh constants
__global__ __launch_bounds__(64) void k_cvec(
    const float* __restrict__ qpart, const float* __restrict__ sump2_g,
    const float* __restrict__ Wlin, const float* __restrict__ blin,
    float* __restrict__ cvec_g, float* __restrict__ isv_g) {
  const int bh = blockIdx.x, t = threadIdx.x;
  __shared__ float qs[64];
  float s = 0.f;
#pragma unroll
  for (int on = 0; on < 16; ++on) s += qpart[(size_t)bh * 1024 + on * 64 + t];
  qs[t] = s;
  __syncthreads();
  const float MU = 1.0f / 1024.0f;
  float sp2 = sump2_g[bh] + sump2_g[bh + 256] + sump2_g[bh + 512] + sump2_g[bh + 768];
  float var = sp2 * (1.0f / 1048576.0f) - MU * MU;
  float isv = 1.0f / sqrtf(var + EPS);
  float wq = 0.f;
  for (int d = 0; d < 64; ++d) wq += Wlin[t * 64 + d] * qs[d];
  cvec_g[bh * 64 + t] = blin[t] - isv * MU * wq;
  if (t == 0) isv_g[bh] = isv;
}

// ---------------- K3b: out = isv * P_out + cvec[e] + x
__global__ __launch_bounds__(256) void k_fin(
    float* __restrict__ out, const float* __restrict__ x,
    const float* __restrict__ cvec_g, const float* __restrict__ isv_g) {
  const int bid = blockIdx.x, t = threadIdx.x;
  const int bh = bid >> 3, part = bid & 7;
  const float isv = isv_g[bh];
  const size_t base = (size_t)bh * 65536 + part * 8192;
#pragma unroll
  for (int it = 0; it < 8; ++it) {
    size_t off = base + it * 1024 + t * 4;
    float cv = cvec_g[bh * 64 + part * 8 + it];
    f32x4 po = *(const f32x4*)(out + off);
    f32x4 xv = *(const f32x4*)(x + off);
    f32x4 res;
#pragma unroll
    for (int k = 0; k < 4; ++k) res[k] = isv * po[k] + cv + xv[k];
    *(f32x4*)(out + off) = res;
  }
}

extern "C" void kernel_launch(void* const* d_in, const int* in_sizes, int n_in,
                              void* d_out, int out_size, void* d_ws, size_t ws_size,
                              hipStream_t stream) {
  const float* x = (const float*)d_in[0];
  const float* Ws = (const float*)d_in[1];
  const float* bs = (const float*)d_in[2];
  const float* rh = (const float*)d_in[3];
  const float* rw = (const float*)d_in[4];
  const float* Wl = (const float*)d_in[5];
  const float* bl = (const float*)d_in[6];
  char* wsb = (char*)d_ws;
  u16* qh = (u16*)wsb;                               // 32 MiB  q f16, n-major [bh][n][d]
  u16* vw = (u16*)(wsb + (size_t)67108864);          // 32 MiB  Vw f16, d-major [bh][e][n]
  float* pos_t = (float*)(wsb + (size_t)100663296);  //  2 MiB  pos [h][n][d]
  float* qpart = (float*)(wsb + (size_t)102760448);  //  1 MiB  qsum partials
  float* s2g = (float*)(wsb + (size_t)103809024);    //  4 KiB
  float* cvec = (float*)(wsb + (size_t)103813120);   // 64 KiB
  float* isvg = (float*)(wsb + (size_t)103878656);   //  1 KiB
  u16* wsh = (u16*)(wsb + (size_t)103880704);        // 512 KiB W_start bf16 hi
  u16* wsl = (u16*)(wsb + (size_t)104404992);        // 512 KiB W_start bf16 lo
  float* out = (float*)d_out;

  k_init<<<2304, 256, 0, stream>>>(Ws, wsh, wsl, rh, rw, pos_t);
  k_conv<<<dim3(16, 32), 256, 0, stream>>>(x, wsh, wsl, bs, qh, qpart);
  k_vw<<<512, 256, 0, stream>>>(qh, Wl, vw);
  k_attn<<<1024, 512, 0, stream>>>(qh, vw, pos_t, out, s2g);
  k_cvec<<<256, 64, 0, stream>>>(qpart, s2g, Wl, bl, cvec, isvg);
  k_fin<<<2048, 256, 0, stream>>>(out, x, cvec, isvg);
}

// Round 20
// 193.566 us; speedup vs baseline: 2.6860x; 1.2513x over previous
//
#include <hip/hip_runtime.h>

#define EPS 1e-5f

typedef unsigned short u16;
typedef unsigned int u32;
typedef _Float16 f16;
typedef __attribute__((ext_vector_type(8))) u16 u16x8;
typedef __attribute__((ext_vector_type(2))) u32 u32x2;
typedef __attribute__((ext_vector_type(4))) u32 u32x4;
typedef __attribute__((ext_vector_type(8))) f16 f16x8;
typedef __attribute__((ext_vector_type(2))) f16 f16x2;
typedef __attribute__((ext_vector_type(4))) float f32x4;
typedef __attribute__((ext_vector_type(2))) float f32x2;

typedef __attribute__((address_space(3))) u32 lds_u32;
typedef __attribute__((address_space(1))) const u32 gbl_u32;

__device__ __forceinline__ u32 pk2h(float a, float b) {  // f16 pair, elt0 low, RNE
  f32x2 v = {a, b};
  return __builtin_bit_cast(u32, __builtin_convertvector(v, f16x2));
}
__device__ __forceinline__ float h2f(u16 u) {
  return (float)__builtin_bit_cast(f16, u);
}
__device__ __forceinline__ f32x4 mfma16h(u16x8 a, u16x8 b, f32x4 c) {  // f16
  return __builtin_amdgcn_mfma_f32_16x16x32_f16(
      __builtin_bit_cast(f16x8, a), __builtin_bit_cast(f16x8, b), c, 0, 0, 0);
}
__device__ __forceinline__ void gl16(const u16* g, u16* l) {
  __builtin_amdgcn_global_load_lds((gbl_u32*)g, (lds_u32*)l, 16, 0, 0);
}

// ps/p2 accumulation from a packed f16 pair: fdot2 when available, f32 fallback.
#if __has_builtin(__builtin_amdgcn_fdot2)
#define ACC_PS_P2(wrd, ps, p2)                                          \
  do {                                                                  \
    f16x2 _h = __builtin_bit_cast(f16x2, (u32)(wrd));                   \
    f16x2 _one = {(f16)1.0f, (f16)1.0f};                                \
    ps = __builtin_amdgcn_fdot2(_h, _one, ps, false);                   \
    p2 = __builtin_amdgcn_fdot2(_h, _h, p2, false);                     \
  } while (0)
#else
#define ACC_PS_P2(wrd, ps, p2)                                          \
  do {                                                                  \
    float _a = h2f((u16)(wrd)), _b = h2f((u16)((wrd) >> 16));           \
    ps += _a + _b;                                                      \
    p2 = fmaf(_a, _a, fmaf(_b, _b, p2));                                \
  } while (0)
#endif

// ---------------- K_init: W_start -> f16 single plane (blocks 0..255) + pos table
__global__ __launch_bounds__(256) void k_init(
    const float* __restrict__ Ws, u16* __restrict__ wsh,
    const float* __restrict__ rel_h, const float* __restrict__ rel_w,
    float* __restrict__ pos_t) {
  int bid = blockIdx.x;
  if (bid < 256) {
    int i = (bid * 256 + threadIdx.x) * 4;
    f32x4 v = *(const f32x4*)(Ws + i);
    u32 h01 = pk2h(v[0], v[1]), h23 = pk2h(v[2], v[3]);
    u32x2 hh = {h01, h23};
    *(u32x2*)(wsh + i) = hh;
  } else {
    int t = (bid - 256) * 256 + threadIdx.x;  // 524288 exact
    int d = t & 63;
    int n = (t >> 6) & 1023;
    int h = t >> 16;
    int hh = n & 31, ww = n >> 5;
    pos_t[t] = rel_h[(h * 64 + d) * 32 + hh] + rel_w[(h * 64 + d) * 32 + ww];
  }
}

// ---------------- K1: s = W_start @ x + b -> qh (single f16) + qsum partials.
// Single-term f16 MFMA. Count-robust staging: full vmcnt(0) drain before each
// buffer read; next stage issued AFTER the reads (hidden by 1-iter distance).
__global__ __launch_bounds__(256, 2) void k_conv(
    const float* __restrict__ x, const u16* __restrict__ wsh,
    const float* __restrict__ bs, u16* __restrict__ qh, float* __restrict__ qpart) {
  __shared__ u16 xt_h[64 * 72];
  __shared__ __align__(16) u16 wbuf[3][4096];  // [buf][64*64] f16, 24KB
  const int on = blockIdx.x, b = blockIdx.y, n0 = on * 64;
  const int t = threadIdx.x, w = t >> 6, lane = t & 63, g = lane >> 4, li = lane & 15;
  const int r8 = lane >> 3, c8 = (lane & 7) ^ r8;
  f32x4 zz = {0.f, 0.f, 0.f, 0.f};
  f32x4 acc[8][4];
#pragma unroll
  for (int ob = 0; ob < 8; ++ob)
#pragma unroll
    for (int i = 0; i < 4; ++i) acc[ob][i] = zz;

#define WSTAGE(buf, ob_, c0_)                                                 \
  do {                                                                        \
    _Pragma("unroll") for (int p = 0; p < 2; ++p) {                           \
      int rq = (ob_) * 64 + 16 * w + 8 * p + r8;                              \
      gl16(wsh + (size_t)rq * 512 + (c0_) + 8 * c8,                           \
           &wbuf[buf][(16 * w + 8 * p) * 64]);                                \
    }                                                                         \
  } while (0)

  for (int kc = 0; kc < 8; ++kc) {
    const int c0 = kc * 64;
    __syncthreads();
    int c = t >> 2, ns = (t & 3) * 16;
    const float* src = x + ((size_t)b * 512 + c0 + c) * 1024 + n0 + ns;
    f32x4 xr[4];
#pragma unroll
    for (int k = 0; k < 4; ++k) xr[k] = *(const f32x4*)(src + 4 * k);
    WSTAGE(0, 0, c0);
    WSTAGE(1, 1, c0);
#pragma unroll
    for (int k = 0; k < 4; ++k)
#pragma unroll
      for (int j = 0; j < 4; ++j) {
        int n = ns + 4 * k + j;
        xt_h[n * 72 + c] = __builtin_bit_cast(u16, (f16)xr[k][j]);
      }
    __syncthreads();  // xt visible; W bufs 0,1 + x drained by barrier
    u16x8 bx[2][4];
#pragma unroll
    for (int ks = 0; ks < 2; ++ks)
#pragma unroll
      for (int nf = 0; nf < 4; ++nf)
        bx[ks][nf] = *(const u16x8*)&xt_h[(16 * nf + li) * 72 + g * 8 + 32 * ks];
#pragma unroll
    for (int ob = 0; ob < 8; ++ob) {
      // Full drain: robust to ANY unaccounted VMEM ops (hoisted loads, spills).
      asm volatile("s_waitcnt vmcnt(0)" ::: "memory");
      const char* wb = (const char*)&wbuf[ob % 3][0];
      u16x8 ah[2];
#pragma unroll
      for (int ks = 0; ks < 2; ++ks) {
        int off = (16 * w + li) * 128 + (((4 * ks + g) * 16) ^ ((li & 7) << 4));
        ah[ks] = *(const u16x8*)(wb + off);
      }
      if (ob < 6) WSTAGE((ob + 2) % 3, ob + 2, c0);
#pragma unroll
      for (int ks = 0; ks < 2; ++ks)
#pragma unroll
        for (int nf = 0; nf < 4; ++nf)
          acc[ob][nf] = mfma16h(ah[ks], bx[ks][nf], acc[ob][nf]);
    }
  }
#undef WSTAGE
  // ---- epilogue: bias, q stores as single f16, qsum partials
#pragma unroll
  for (int ob = 0; ob < 8; ++ob) {
    const int o0 = ob * 64, bh = b * 8 + ob;
    float bias[4];
#pragma unroll
    for (int r = 0; r < 4; ++r) bias[r] = bs[o0 + 16 * w + g * 4 + r];
    float vq[4] = {0.f, 0.f, 0.f, 0.f};
#pragma unroll
    for (int nf = 0; nf < 4; ++nf) {
      float v0 = acc[ob][nf][0] + bias[0], v1 = acc[ob][nf][1] + bias[1];
      float v2 = acc[ob][nf][2] + bias[2], v3 = acc[ob][nf][3] + bias[3];
      vq[0] += v0; vq[1] += v1; vq[2] += v2; vq[3] += v3;
      u32 h01 = pk2h(v0, v1), h23 = pk2h(v2, v3);
      size_t base = ((size_t)bh * 1024 + n0 + 16 * nf + li) * 64 + 16 * w + g * 4;
      u32x2 ph = {h01, h23};
      *(u32x2*)(qh + base) = ph;
    }
#pragma unroll
    for (int r = 0; r < 4; ++r) {
      float s = vq[r];
      s += __shfl_xor(s, 1, 64);
      s += __shfl_xor(s, 2, 64);
      s += __shfl_xor(s, 4, 64);
      s += __shfl_xor(s, 8, 64);
      if (li == 0) qpart[((size_t)bh * 16 + on) * 64 + 16 * w + 4 * g + r] = s;
    }
  }
}

// ---------------- K_vw: Vw = W_lin @ q per (bh, n-half); q single f16, W 2-term.
// (R17 verbatim)
__global__ __launch_bounds__(256) void k_vw(
    const u16* __restrict__ qh, const float* __restrict__ Wlin, u16* __restrict__ vw) {
  __shared__ __align__(16) u16 qbuf[2][4096];  // [buf][64n x 64d] 16KB
  __shared__ u16 lw_h[64 * 72], lw_l[64 * 72];
  __shared__ u16 bounce[64 * 72];
  const int bh = blockIdx.x >> 1, half = blockIdx.x & 1;
  const int t = threadIdx.x, w = t >> 6, lane = t & 63, g = lane >> 4, li = lane & 15;
  const int r8 = lane >> 3, c8 = (lane & 7) ^ r8;
  const u16* qhb = qh + (size_t)bh * 65536;
  f32x4 zz = {0.f, 0.f, 0.f, 0.f};

  {  // stage W_lin split (f16 hi/lo)
    int e = t >> 2, ds = (t & 3) * 16;
    const float* src = Wlin + e * 64 + ds;
    float arr[16];
#pragma unroll
    for (int k = 0; k < 4; ++k) *(f32x4*)&arr[4 * k] = *(const f32x4*)(src + 4 * k);
#pragma unroll
    for (int p = 0; p < 8; ++p) {
      float a = arr[2 * p], c = arr[2 * p + 1];
      u32 hw = pk2h(a, c);
      u32 lw = pk2h(a - h2f((u16)hw), c - h2f((u16)(hw >> 16)));
      *(u32*)&lw_h[e * 72 + ds + 2 * p] = hw;
      *(u32*)&lw_l[e * 72 + ds + 2 * p] = lw;
    }
  }
#define STAGE_Q(bb, n0_)                                                      \
  do {                                                                        \
    _Pragma("unroll") for (int p = 0; p < 2; ++p) {                           \
      int rq = (n0_) + 8 * (w + 4 * p) + r8;                                  \
      gl16(qhb + (size_t)rq * 64 + 8 * c8, &qbuf[bb][(8 * (w + 4 * p)) * 64]); \
    }                                                                         \
  } while (0)

  const int nt0 = half * 8;
  STAGE_Q(0, nt0 * 64);
  __syncthreads();
  u16x8 la_h[2], la_l[2];
#pragma unroll
  for (int ks = 0; ks < 2; ++ks) {
    la_h[ks] = *(const u16x8*)&lw_h[(16 * w + li) * 72 + g * 8 + 32 * ks];
    la_l[ks] = *(const u16x8*)&lw_l[(16 * w + li) * 72 + g * 8 + 32 * ks];
  }
  int cur = 0;
  for (int it = 0; it < 8; ++it) {
    const int nt = nt0 + it;
    if (it < 7) STAGE_Q(cur ^ 1, (nt + 1) * 64);
    f32x4 acc2[4] = {zz, zz, zz, zz};
    const char* qb0 = (const char*)&qbuf[cur][0];
#pragma unroll
    for (int ks = 0; ks < 2; ++ks)
#pragma unroll
      for (int nf = 0; nf < 4; ++nf) {
        int off = (16 * nf + li) * 128 + (((4 * ks + g) * 16) ^ ((li & 7) << 4));
        u16x8 qv = *(const u16x8*)(qb0 + off);
        acc2[nf] = mfma16h(la_h[ks], qv, acc2[nf]);
        acc2[nf] = mfma16h(la_l[ks], qv, acc2[nf]);
      }
    __syncthreads();
#pragma unroll
    for (int nf = 0; nf < 4; ++nf)
#pragma unroll
      for (int r = 0; r < 4; ++r)
        bounce[(16 * w + 4 * g + r) * 72 + 16 * nf + li] =
            __builtin_bit_cast(u16, (f16)acc2[nf][r]);
    __syncthreads();
    {  // coalesced Vw store: [bh][e][n]
      int e = t >> 2, nc = (t & 3) * 16;
      u16x8 v0 = *(const u16x8*)&bounce[e * 72 + nc];
      u16x8 v1 = *(const u16x8*)&bounce[e * 72 + nc + 8];
      size_t base = ((size_t)bh * 64 + e) * 1024 + nt * 64 + nc;
      *(u16x8*)(vw + base) = v0;
      *(u16x8*)(vw + base + 8) = v1;
    }
    cur ^= 1;
  }
#undef STAGE_Q
}

// ---------------- K2: flash attention (R17 verbatim)
__global__ __launch_bounds__(512, 4) void k_attn(
    const u16* __restrict__ qh, const u16* __restrict__ vw,
    const float* __restrict__ pos_t, float* __restrict__ pout, float* __restrict__ sump2_g) {
  __shared__ __align__(16) char smem[49184];  // kbuf 32K | ptw 8x2K | wvar 32B
  u16(*kbuf)[2][4096] = (u16(*)[2][4096])smem;  // [buf][{kh,vw}][64*64]
  float* wvar = (float*)(smem + 49152);
  const int bid = blockIdx.x, bh = bid & 255, quarter = bid >> 8;
  const int b = bh >> 3, h = bh & 7;
  const int t = threadIdx.x, w = t >> 6, lane = t & 63, g = lane >> 4, li = lane & 15;
  char* ptw = smem + 32768 + w * 2048;
  const u16* qhb = qh + (size_t)bh * 65536;
  const u16* vwb = vw + (size_t)bh * 65536;
  const float* posb = pos_t + (size_t)h * 65536;
  const float SIL = 0.088388347648318447f * 1.4426950408889634f;
  const float L2E = 1.4426950408889634f;
  const int swz = (li & 7) << 4;
  f32x4 zz = {0.f, 0.f, 0.f, 0.f};

  u16x8 qb_h[2][2];
  const int jr0 = quarter * 256 + 16 * w;
#pragma unroll
  for (int s = 0; s < 2; ++s) {
    int jr = jr0 + s * 128 + li;
#pragma unroll
    for (int ks = 0; ks < 2; ++ks) {
      int dc = 32 * ks + 8 * g;
      u16x8 hh = *(const u16x8*)(qhb + (size_t)jr * 64 + dc);
      const float* sp = posb + (size_t)jr * 64 + dc;
      f32x4 p0 = *(const f32x4*)sp, p1 = *(const f32x4*)(sp + 4);
      u32 AW[4];
#pragma unroll
      for (int p = 0; p < 4; ++p) {
        float pa = (2 * p < 4) ? p0[2 * p] : p1[2 * p - 4];
        float pb = (2 * p + 1 < 4) ? p0[2 * p + 1] : p1[2 * p - 3];
        float v0 = h2f(hh[2 * p]) * SIL + pa * L2E;
        float v1 = h2f(hh[2 * p + 1]) * SIL + pb * L2E;
        AW[p] = pk2h(v0, v1);
      }
      u32x4 av = {AW[0], AW[1], AW[2], AW[3]};
      qb_h[s][ks] = __builtin_bit_cast(u16x8, av);
    }
  }

#define STAGE(bb, k0)                                                         \
  do {                                                                        \
    int r8 = lane >> 3, c8 = (lane & 7) ^ r8;                                 \
    int rq = (k0) + 8 * w + r8;                                               \
    gl16(qhb + (size_t)rq * 64 + 8 * c8, &kbuf[bb][0][w * 512]);              \
    gl16(vwb + (size_t)(8 * w + r8) * 1024 + (k0) + 8 * c8,                   \
         &kbuf[bb][1][w * 512]);                                              \
  } while (0)

  float m0 = -3.0e38f, l0 = 0.f, s20 = 0.f;
  float m1 = -3.0e38f, l1 = 0.f, s21 = 0.f;
  f32x4 O0[4], O1[4];
#pragma unroll
  for (int df = 0; df < 4; ++df) {
    O0[df] = zz;
    O1[df] = zz;
  }

#define SOFT(S, mm, ll, ss2, O)                                               \
  do {                                                                        \
    float t0 = fmaxf(fmaxf(S[0][0], S[0][1]), fmaxf(S[0][2], S[0][3]));       \
    float t1 = fmaxf(fmaxf(S[1][0], S[1][1]), fmaxf(S[1][2], S[1][3]));       \
    float t2 = fmaxf(fmaxf(S[2][0], S[2][1]), fmaxf(S[2][2], S[2][3]));       \
    float t3 = fmaxf(fmaxf(S[3][0], S[3][1]), fmaxf(S[3][2], S[3][3]));       \
    float tl = fmaxf(fmaxf(t0, t1), fmaxf(t2, t3));                           \
    if (__any(tl > mm + 12.f)) {                                              \
      float tm = fmaxf(tl, __shfl_xor(tl, 16, 64));                           \
      tm = fmaxf(tm, __shfl_xor(tm, 32, 64));                                 \
      float mn = fmaxf(mm, tm);                                               \
      float cr = __builtin_amdgcn_exp2f(mm - mn);                             \
      mm = mn;                                                                \
      ll *= cr;                                                               \
      ss2 *= cr * cr;                                                         \
      _Pragma("unroll") for (int df = 0; df < 4; ++df) O[df] *= cr;           \
    }                                                                         \
    _Pragma("unroll") for (int nf = 0; nf < 4; ++nf) {                        \
      _Pragma("unroll") for (int r = 0; r < 4; ++r)                           \
        S[nf][r] = __builtin_amdgcn_exp2f(S[nf][r] - mm);                     \
    }                                                                         \
    float ps = 0.f, p2 = 0.f;                                                 \
    _Pragma("unroll") for (int nf = 0; nf < 4; ++nf) {                        \
      u32 w0 = pk2h(S[nf][0], S[nf][1]);                                      \
      u32 w1 = pk2h(S[nf][2], S[nf][3]);                                      \
      ACC_PS_P2(w0, ps, p2);                                                  \
      ACC_PS_P2(w1, ps, p2);                                                  \
      int slot = 2 * nf + (g >> 1);                                           \
      u32x2 pk = {w0, w1};                                                    \
      *(u32x2*)(ptw + li * 128 + ((slot * 16) ^ swz) + (g & 1) * 8) = pk;     \
    }                                                                         \
    ll += ps;                                                                 \
    ss2 += p2;                                                                \
  } while (0)

  int cur = 0;
  STAGE(0, 0);
  __syncthreads();
  for (int kc = 0; kc < 16; ++kc) {
    if (kc < 15) STAGE(cur ^ 1, (kc + 1) * 64);
    const char* kb = (const char*)&kbuf[cur][0][0];
    const char* vb = (const char*)&kbuf[cur][1][0];
    f32x4 S0[4] = {zz, zz, zz, zz};
    f32x4 S1[4] = {zz, zz, zz, zz};
    __builtin_amdgcn_s_setprio(1);
#pragma unroll
    for (int ks = 0; ks < 2; ++ks) {
#pragma unroll
      for (int nf = 0; nf < 4; ++nf) {
        int off = (16 * nf + li) * 128 + (((4 * ks + g) * 16) ^ swz);
        u16x8 kh = *(const u16x8*)(kb + off);
        S0[nf] = mfma16h(kh, qb_h[0][ks], S0[nf]);
        S1[nf] = mfma16h(kh, qb_h[1][ks], S1[nf]);
      }
    }
    __builtin_amdgcn_s_setprio(0);
    SOFT(S0, m0, l0, s20, O0);
    u16x8 pb0[2];
    pb0[0] = *(const u16x8*)(ptw + li * 128 + ((g * 16) ^ swz));
    pb0[1] = *(const u16x8*)(ptw + li * 128 + (((4 + g) * 16) ^ swz));
    SOFT(S1, m1, l1, s21, O1);
    u16x8 pb1[2];
    pb1[0] = *(const u16x8*)(ptw + li * 128 + ((g * 16) ^ swz));
    pb1[1] = *(const u16x8*)(ptw + li * 128 + (((4 + g) * 16) ^ swz));
    __builtin_amdgcn_s_setprio(1);
#pragma unroll
    for (int ks = 0; ks < 2; ++ks) {
#pragma unroll
      for (int df = 0; df < 4; ++df) {
        u16x8 va = *(const u16x8*)(vb + (16 * df + li) * 128 + (((4 * ks + g) * 16) ^ swz));
        O0[df] = mfma16h(va, pb0[ks], O0[df]);
        O1[df] = mfma16h(va, pb1[ks], O1[df]);
      }
    }
    __builtin_amdgcn_s_setprio(0);
    __syncthreads();
    cur ^= 1;
  }

  float wacc = 0.f;
  l0 += __shfl_xor(l0, 16, 64);
  l0 += __shfl_xor(l0, 32, 64);
  s20 += __shfl_xor(s20, 16, 64);
  s20 += __shfl_xor(s20, 32, 64);
  l1 += __shfl_xor(l1, 16, 64);
  l1 += __shfl_xor(l1, 32, 64);
  s21 += __shfl_xor(s21, 16, 64);
  s21 += __shfl_xor(s21, 32, 64);
  float il0 = 1.0f / l0, il1 = 1.0f / l1;
#pragma unroll
  for (int df = 0; df < 4; ++df) {
    O0[df] *= il0;
    O1[df] *= il1;
  }
  {
    float s2w = s20 * il0 * il0;
    s2w += __shfl_xor(s2w, 1, 64);
    s2w += __shfl_xor(s2w, 2, 64);
    s2w += __shfl_xor(s2w, 4, 64);
    s2w += __shfl_xor(s2w, 8, 64);
    wacc += s2w;
    float s2w1 = s21 * il1 * il1;
    s2w1 += __shfl_xor(s2w1, 1, 64);
    s2w1 += __shfl_xor(s2w1, 2, 64);
    s2w1 += __shfl_xor(s2w1, 4, 64);
    s2w1 += __shfl_xor(s2w1, 8, 64);
    wacc += s2w1;
  }
  if (lane == 0) wvar[w] = wacc;

  float* bounce = (float*)smem;  // [64 e][132] f32 = 33792B
#pragma unroll
  for (int s = 0; s < 2; ++s) {
    const int jg0 = quarter * 256 + s * 128;
    __syncthreads();
#pragma unroll
    for (int df = 0; df < 4; ++df)
#pragma unroll
      for (int r = 0; r < 4; ++r)
        bounce[(df * 16 + g * 4 + r) * 132 + 16 * w + li] = s ? O1[df][r] : O0[df][r];
    __syncthreads();
#pragma unroll
    for (int p = 0; p < 4; ++p) {
      int idx = p * 512 + t;
      int e = idx >> 5, ch = idx & 31;
      f32x4 v = *(const f32x4*)&bounce[e * 132 + ch * 4];
      *(f32x4*)&pout[((size_t)b * 512 + h * 64 + e) * 1024 + jg0 + ch * 4] = v;
    }
  }
  __syncthreads();
  if (t == 0) {
    float s = 0.f;
#pragma unroll
    for (int i = 0; i < 8; ++i) s += wvar[i];
    sump2_g[bid] = s;
  }
#undef STAGE
#undef SOFT
}

// ---------------- K3a: per-bh constants
__global__ __launch_bounds__(64) void k_cvec(
    const float* __restrict__ qpart, const float* __restrict__ sump2_g,
    const float* __restrict__ Wlin, const float* __restrict__ blin,
    float* __restrict__ cvec_g, float* __restrict__ isv_g) {
  const int bh = blockIdx.x, t = threadIdx.x;
  __shared__ float qs[64];
  float s = 0.f;
#pragma unroll
  for (int on = 0; on < 16; ++on) s += qpart[(size_t)bh * 1024 + on * 64 + t];
  qs[t] = s;
  __syncthreads();
  const float MU = 1.0f / 1024.0f;
  float sp2 = sump2_g[bh] + sump2_g[bh + 256] + sump2_g[bh + 512] + sump2_g[bh + 768];
  float var = sp2 * (1.0f / 1048576.0f) - MU * MU;
  float isv = 1.0f / sqrtf(var + EPS);
  float wq = 0.f;
  for (int d = 0; d < 64; ++d) wq += Wlin[t * 64 + d] * qs[d];
  cvec_g[bh * 64 + t] = blin[t] - isv * MU * wq;
  if (t == 0) isv_g[bh] = isv;
}

// ---------------- K3b: out = isv * P_out + cvec[e] + x
__global__ __launch_bounds__(256) void k_fin(
    float* __restrict__ out, const float* __restrict__ x,
    const float* __restrict__ cvec_g, const float* __restrict__ isv_g) {
  const int bid = blockIdx.x, t = threadIdx.x;
  const int bh = bid >> 3, part = bid & 7;
  const float isv = isv_g[bh];
  const size_t base = (size_t)bh * 65536 + part * 8192;
#pragma unroll
  for (int it = 0; it < 8; ++it) {
    size_t off = base + it * 1024 + t * 4;
    float cv = cvec_g[bh * 64 + part * 8 + it];
    f32x4 po = *(const f32x4*)(out + off);
    f32x4 xv = *(const f32x4*)(x + off);
    f32x4 res;
#pragma unroll
    for (int k = 0; k < 4; ++k) res[k] = isv * po[k] + cv + xv[k];
    *(f32x4*)(out + off) = res;
  }
}

extern "C" void kernel_launch(void* const* d_in, const int* in_sizes, int n_in,
                              void* d_out, int out_size, void* d_ws, size_t ws_size,
                              hipStream_t stream) {
  const float* x = (const float*)d_in[0];
  const float* Ws = (const float*)d_in[1];
  const float* bs = (const float*)d_in[2];
  const float* rh = (const float*)d_in[3];
  const float* rw = (const float*)d_in[4];
  const float* Wl = (const float*)d_in[5];
  const float* bl = (const float*)d_in[6];
  char* wsb = (char*)d_ws;
  u16* qh = (u16*)wsb;                               // 32 MiB  q f16, n-major [bh][n][d]
  u16* vw = (u16*)(wsb + (size_t)67108864);          // 32 MiB  Vw f16, d-major [bh][e][n]
  float* pos_t = (float*)(wsb + (size_t)100663296);  //  2 MiB  pos [h][n][d]
  float* qpart = (float*)(wsb + (size_t)102760448);  //  1 MiB  qsum partials
  float* s2g = (float*)(wsb + (size_t)103809024);    //  4 KiB
  float* cvec = (float*)(wsb + (size_t)103813120);   // 64 KiB
  float* isvg = (float*)(wsb + (size_t)103878656);   //  1 KiB
  u16* wsh = (u16*)(wsb + (size_t)103880704);        // 512 KiB W_start f16
  float* out = (float*)d_out;

  k_init<<<2304, 256, 0, stream>>>(Ws, wsh, rh, rw, pos_t);
  k_conv<<<dim3(16, 32), 256, 0, stream>>>(x, wsh, bs, qh, qpart);
  k_vw<<<512, 256, 0, stream>>>(qh, Wl, vw);
  k_attn<<<1024, 512, 0, stream>>>(qh, vw, pos_t, out, s2g);
  k_cvec<<<256, 64, 0, stream>>>(qpart, s2g, Wl, bl, cvec, isvg);
  k_fin<<<2048, 256, 0, stream>>>(out, x, cvec, isvg);
}

// Round 21
// 192.920 us; speedup vs baseline: 2.6950x; 1.0033x over previous
//
#include <hip/hip_runtime.h>

#define EPS 1e-5f

typedef unsigned short u16;
typedef unsigned int u32;
typedef _Float16 f16;
typedef __attribute__((ext_vector_type(8))) u16 u16x8;
typedef __attribute__((ext_vector_type(2))) u32 u32x2;
typedef __attribute__((ext_vector_type(4))) u32 u32x4;
typedef __attribute__((ext_vector_type(8))) f16 f16x8;
typedef __attribute__((ext_vector_type(2))) f16 f16x2;
typedef __attribute__((ext_vector_type(4))) float f32x4;
typedef __attribute__((ext_vector_type(2))) float f32x2;

typedef __attribute__((address_space(3))) u32 lds_u32;
typedef __attribute__((address_space(1))) const u32 gbl_u32;

__device__ __forceinline__ u32 pk2h(float a, float b) {  // f16 pair, elt0 low, RNE
  f32x2 v = {a, b};
  return __builtin_bit_cast(u32, __builtin_convertvector(v, f16x2));
}
__device__ __forceinline__ float h2f(u16 u) {
  return (float)__builtin_bit_cast(f16, u);
}
__device__ __forceinline__ f32x4 mfma16h(u16x8 a, u16x8 b, f32x4 c) {  // f16
  return __builtin_amdgcn_mfma_f32_16x16x32_f16(
      __builtin_bit_cast(f16x8, a), __builtin_bit_cast(f16x8, b), c, 0, 0, 0);
}
__device__ __forceinline__ void gl16(const u16* g, u16* l) {
  __builtin_amdgcn_global_load_lds((gbl_u32*)g, (lds_u32*)l, 16, 0, 0);
}

// ps/p2 accumulation from a packed f16 pair: fdot2 when available, f32 fallback.
#if __has_builtin(__builtin_amdgcn_fdot2)
#define ACC_PS_P2(wrd, ps, p2)                                          \
  do {                                                                  \
    f16x2 _h = __builtin_bit_cast(f16x2, (u32)(wrd));                   \
    f16x2 _one = {(f16)1.0f, (f16)1.0f};                                \
    ps = __builtin_amdgcn_fdot2(_h, _one, ps, false);                   \
    p2 = __builtin_amdgcn_fdot2(_h, _h, p2, false);                     \
  } while (0)
#else
#define ACC_PS_P2(wrd, ps, p2)                                          \
  do {                                                                  \
    float _a = h2f((u16)(wrd)), _b = h2f((u16)((wrd) >> 16));           \
    ps += _a + _b;                                                      \
    p2 = fmaf(_a, _a, fmaf(_b, _b, p2));                                \
  } while (0)
#endif

// ---------------- K_init: W_start -> f16 single plane (blocks 0..255) + pos table
__global__ __launch_bounds__(256) void k_init(
    const float* __restrict__ Ws, u16* __restrict__ wsh,
    const float* __restrict__ rel_h, const float* __restrict__ rel_w,
    float* __restrict__ pos_t) {
  int bid = blockIdx.x;
  if (bid < 256) {
    int i = (bid * 256 + threadIdx.x) * 4;
    f32x4 v = *(const f32x4*)(Ws + i);
    u32 h01 = pk2h(v[0], v[1]), h23 = pk2h(v[2], v[3]);
    u32x2 hh = {h01, h23};
    *(u32x2*)(wsh + i) = hh;
  } else {
    int t = (bid - 256) * 256 + threadIdx.x;  // 524288 exact
    int d = t & 63;
    int n = (t >> 6) & 1023;
    int h = t >> 16;
    int hh = n & 31, ww = n >> 5;
    pos_t[t] = rel_h[(h * 64 + d) * 32 + hh] + rel_w[(h * 64 + d) * 32 + ww];
  }
}

// ---------------- K1: s = W_start @ x + b -> qh (single f16) + qsum partials.
// Single-term f16 MFMA. Count-robust staging: full vmcnt(0) drain before each
// buffer read; next stage issued AFTER the reads (hidden by 1-iter distance).
__global__ __launch_bounds__(256, 2) void k_conv(
    const float* __restrict__ x, const u16* __restrict__ wsh,
    const float* __restrict__ bs, u16* __restrict__ qh, float* __restrict__ qpart) {
  __shared__ u16 xt_h[64 * 72];
  __shared__ __align__(16) u16 wbuf[3][4096];  // [buf][64*64] f16, 24KB
  const int on = blockIdx.x, b = blockIdx.y, n0 = on * 64;
  const int t = threadIdx.x, w = t >> 6, lane = t & 63, g = lane >> 4, li = lane & 15;
  const int r8 = lane >> 3, c8 = (lane & 7) ^ r8;
  f32x4 zz = {0.f, 0.f, 0.f, 0.f};
  f32x4 acc[8][4];
#pragma unroll
  for (int ob = 0; ob < 8; ++ob)
#pragma unroll
    for (int i = 0; i < 4; ++i) acc[ob][i] = zz;

#define WSTAGE(buf, ob_, c0_)                                                 \
  do {                                                                        \
    _Pragma("unroll") for (int p = 0; p < 2; ++p) {                           \
      int rq = (ob_) * 64 + 16 * w + 8 * p + r8;                              \
      gl16(wsh + (size_t)rq * 512 + (c0_) + 8 * c8,                           \
           &wbuf[buf][(16 * w + 8 * p) * 64]);                                \
    }                                                                         \
  } while (0)

  for (int kc = 0; kc < 8; ++kc) {
    const int c0 = kc * 64;
    __syncthreads();
    int c = t >> 2, ns = (t & 3) * 16;
    const float* src = x + ((size_t)b * 512 + c0 + c) * 1024 + n0 + ns;
    f32x4 xr[4];
#pragma unroll
    for (int k = 0; k < 4; ++k) xr[k] = *(const f32x4*)(src + 4 * k);
    WSTAGE(0, 0, c0);
    WSTAGE(1, 1, c0);
#pragma unroll
    for (int k = 0; k < 4; ++k)
#pragma unroll
      for (int j = 0; j < 4; ++j) {
        int n = ns + 4 * k + j;
        xt_h[n * 72 + c] = __builtin_bit_cast(u16, (f16)xr[k][j]);
      }
    __syncthreads();  // xt visible; W bufs 0,1 + x drained by barrier
    u16x8 bx[2][4];
#pragma unroll
    for (int ks = 0; ks < 2; ++ks)
#pragma unroll
      for (int nf = 0; nf < 4; ++nf)
        bx[ks][nf] = *(const u16x8*)&xt_h[(16 * nf + li) * 72 + g * 8 + 32 * ks];
#pragma unroll
    for (int ob = 0; ob < 8; ++ob) {
      // Full drain: robust to ANY unaccounted VMEM ops (hoisted loads, spills).
      asm volatile("s_waitcnt vmcnt(0)" ::: "memory");
      const char* wb = (const char*)&wbuf[ob % 3][0];
      u16x8 ah[2];
#pragma unroll
      for (int ks = 0; ks < 2; ++ks) {
        int off = (16 * w + li) * 128 + (((4 * ks + g) * 16) ^ ((li & 7) << 4));
        ah[ks] = *(const u16x8*)(wb + off);
      }
      if (ob < 6) WSTAGE((ob + 2) % 3, ob + 2, c0);
#pragma unroll
      for (int ks = 0; ks < 2; ++ks)
#pragma unroll
        for (int nf = 0; nf < 4; ++nf)
          acc[ob][nf] = mfma16h(ah[ks], bx[ks][nf], acc[ob][nf]);
    }
  }
#undef WSTAGE
  // ---- epilogue: bias, q stores as single f16, qsum partials
#pragma unroll
  for (int ob = 0; ob < 8; ++ob) {
    const int o0 = ob * 64, bh = b * 8 + ob;
    float bias[4];
#pragma unroll
    for (int r = 0; r < 4; ++r) bias[r] = bs[o0 + 16 * w + g * 4 + r];
    float vq[4] = {0.f, 0.f, 0.f, 0.f};
#pragma unroll
    for (int nf = 0; nf < 4; ++nf) {
      float v0 = acc[ob][nf][0] + bias[0], v1 = acc[ob][nf][1] + bias[1];
      float v2 = acc[ob][nf][2] + bias[2], v3 = acc[ob][nf][3] + bias[3];
      vq[0] += v0; vq[1] += v1; vq[2] += v2; vq[3] += v3;
      u32 h01 = pk2h(v0, v1), h23 = pk2h(v2, v3);
      size_t base = ((size_t)bh * 1024 + n0 + 16 * nf + li) * 64 + 16 * w + g * 4;
      u32x2 ph = {h01, h23};
      *(u32x2*)(qh + base) = ph;
    }
#pragma unroll
    for (int r = 0; r < 4; ++r) {
      float s = vq[r];
      s += __shfl_xor(s, 1, 64);
      s += __shfl_xor(s, 2, 64);
      s += __shfl_xor(s, 4, 64);
      s += __shfl_xor(s, 8, 64);
      if (li == 0) qpart[((size_t)bh * 16 + on) * 64 + 16 * w + 4 * g + r] = s;
    }
  }
}

// ---------------- K_vw: Vw = W_lin @ q per (bh, n-half); single-term f16.
__global__ __launch_bounds__(256) void k_vw(
    const u16* __restrict__ qh, const float* __restrict__ Wlin, u16* __restrict__ vw) {
  __shared__ __align__(16) u16 qbuf[2][4096];  // [buf][64n x 64d] 16KB
  __shared__ u16 lw_h[64 * 72];
  __shared__ u16 bounce[64 * 72];
  const int bh = blockIdx.x >> 1, half = blockIdx.x & 1;
  const int t = threadIdx.x, w = t >> 6, lane = t & 63, g = lane >> 4, li = lane & 15;
  const int r8 = lane >> 3, c8 = (lane & 7) ^ r8;
  const u16* qhb = qh + (size_t)bh * 65536;
  f32x4 zz = {0.f, 0.f, 0.f, 0.f};

  {  // stage W_lin (single f16)
    int e = t >> 2, ds = (t & 3) * 16;
    const float* src = Wlin + e * 64 + ds;
    float arr[16];
#pragma unroll
    for (int k = 0; k < 4; ++k) *(f32x4*)&arr[4 * k] = *(const f32x4*)(src + 4 * k);
#pragma unroll
    for (int p = 0; p < 8; ++p)
      *(u32*)&lw_h[e * 72 + ds + 2 * p] = pk2h(arr[2 * p], arr[2 * p + 1]);
  }
#define STAGE_Q(bb, n0_)                                                      \
  do {                                                                        \
    _Pragma("unroll") for (int p = 0; p < 2; ++p) {                           \
      int rq = (n0_) + 8 * (w + 4 * p) + r8;                                  \
      gl16(qhb + (size_t)rq * 64 + 8 * c8, &qbuf[bb][(8 * (w + 4 * p)) * 64]); \
    }                                                                         \
  } while (0)

  const int nt0 = half * 8;
  STAGE_Q(0, nt0 * 64);
  __syncthreads();
  u16x8 la_h[2];
#pragma unroll
  for (int ks = 0; ks < 2; ++ks)
    la_h[ks] = *(const u16x8*)&lw_h[(16 * w + li) * 72 + g * 8 + 32 * ks];
  int cur = 0;
  for (int it = 0; it < 8; ++it) {
    const int nt = nt0 + it;
    if (it < 7) STAGE_Q(cur ^ 1, (nt + 1) * 64);
    f32x4 acc2[4] = {zz, zz, zz, zz};
    const char* qb0 = (const char*)&qbuf[cur][0];
#pragma unroll
    for (int ks = 0; ks < 2; ++ks)
#pragma unroll
      for (int nf = 0; nf < 4; ++nf) {
        int off = (16 * nf + li) * 128 + (((4 * ks + g) * 16) ^ ((li & 7) << 4));
        u16x8 qv = *(const u16x8*)(qb0 + off);
        acc2[nf] = mfma16h(la_h[ks], qv, acc2[nf]);
      }
    __syncthreads();
#pragma unroll
    for (int nf = 0; nf < 4; ++nf)
#pragma unroll
      for (int r = 0; r < 4; ++r)
        bounce[(16 * w + 4 * g + r) * 72 + 16 * nf + li] =
            __builtin_bit_cast(u16, (f16)acc2[nf][r]);
    __syncthreads();
    {  // coalesced Vw store: [bh][e][n]
      int e = t >> 2, nc = (t & 3) * 16;
      u16x8 v0 = *(const u16x8*)&bounce[e * 72 + nc];
      u16x8 v1 = *(const u16x8*)&bounce[e * 72 + nc + 8];
      size_t base = ((size_t)bh * 64 + e) * 1024 + nt * 64 + nc;
      *(u16x8*)(vw + base) = v0;
      *(u16x8*)(vw + base + 8) = v1;
    }
    cur ^= 1;
  }
#undef STAGE_Q
}

// ---------------- K2: flash attention (R20 verbatim)
__global__ __launch_bounds__(512, 4) void k_attn(
    const u16* __restrict__ qh, const u16* __restrict__ vw,
    const float* __restrict__ pos_t, float* __restrict__ pout, float* __restrict__ sump2_g) {
  __shared__ __align__(16) char smem[49184];  // kbuf 32K | ptw 8x2K | wvar 32B
  u16(*kbuf)[2][4096] = (u16(*)[2][4096])smem;  // [buf][{kh,vw}][64*64]
  float* wvar = (float*)(smem + 49152);
  const int bid = blockIdx.x, bh = bid & 255, quarter = bid >> 8;
  const int b = bh >> 3, h = bh & 7;
  const int t = threadIdx.x, w = t >> 6, lane = t & 63, g = lane >> 4, li = lane & 15;
  char* ptw = smem + 32768 + w * 2048;
  const u16* qhb = qh + (size_t)bh * 65536;
  const u16* vwb = vw + (size_t)bh * 65536;
  const float* posb = pos_t + (size_t)h * 65536;
  const float SIL = 0.088388347648318447f * 1.4426950408889634f;
  const float L2E = 1.4426950408889634f;
  const int swz = (li & 7) << 4;
  f32x4 zz = {0.f, 0.f, 0.f, 0.f};

  u16x8 qb_h[2][2];
  const int jr0 = quarter * 256 + 16 * w;
#pragma unroll
  for (int s = 0; s < 2; ++s) {
    int jr = jr0 + s * 128 + li;
#pragma unroll
    for (int ks = 0; ks < 2; ++ks) {
      int dc = 32 * ks + 8 * g;
      u16x8 hh = *(const u16x8*)(qhb + (size_t)jr * 64 + dc);
      const float* sp = posb + (size_t)jr * 64 + dc;
      f32x4 p0 = *(const f32x4*)sp, p1 = *(const f32x4*)(sp + 4);
      u32 AW[4];
#pragma unroll
      for (int p = 0; p < 4; ++p) {
        float pa = (2 * p < 4) ? p0[2 * p] : p1[2 * p - 4];
        float pb = (2 * p + 1 < 4) ? p0[2 * p + 1] : p1[2 * p - 3];
        float v0 = h2f(hh[2 * p]) * SIL + pa * L2E;
        float v1 = h2f(hh[2 * p + 1]) * SIL + pb * L2E;
        AW[p] = pk2h(v0, v1);
      }
      u32x4 av = {AW[0], AW[1], AW[2], AW[3]};
      qb_h[s][ks] = __builtin_bit_cast(u16x8, av);
    }
  }

#define STAGE(bb, k0)                                                         \
  do {                                                                        \
    int r8 = lane >> 3, c8 = (lane & 7) ^ r8;                                 \
    int rq = (k0) + 8 * w + r8;                                               \
    gl16(qhb + (size_t)rq * 64 + 8 * c8, &kbuf[bb][0][w * 512]);              \
    gl16(vwb + (size_t)(8 * w + r8) * 1024 + (k0) + 8 * c8,                   \
         &kbuf[bb][1][w * 512]);                                              \
  } while (0)

  float m0 = -3.0e38f, l0 = 0.f, s20 = 0.f;
  float m1 = -3.0e38f, l1 = 0.f, s21 = 0.f;
  f32x4 O0[4], O1[4];
#pragma unroll
  for (int df = 0; df < 4; ++df) {
    O0[df] = zz;
    O1[df] = zz;
  }

#define SOFT(S, mm, ll, ss2, O)                                               \
  do {                                                                        \
    float t0 = fmaxf(fmaxf(S[0][0], S[0][1]), fmaxf(S[0][2], S[0][3]));       \
    float t1 = fmaxf(fmaxf(S[1][0], S[1][1]), fmaxf(S[1][2], S[1][3]));       \
    float t2 = fmaxf(fmaxf(S[2][0], S[2][1]), fmaxf(S[2][2], S[2][3]));       \
    float t3 = fmaxf(fmaxf(S[3][0], S[3][1]), fmaxf(S[3][2], S[3][3]));       \
    float tl = fmaxf(fmaxf(t0, t1), fmaxf(t2, t3));                           \
    if (__any(tl > mm + 12.f)) {                                              \
      float tm = fmaxf(tl, __shfl_xor(tl, 16, 64));                           \
      tm = fmaxf(tm, __shfl_xor(tm, 32, 64));                                 \
      float mn = fmaxf(mm, tm);                                               \
      float cr = __builtin_amdgcn_exp2f(mm - mn);                             \
      mm = mn;                                                                \
      ll *= cr;                                                               \
      ss2 *= cr * cr;                                                         \
      _Pragma("unroll") for (int df = 0; df < 4; ++df) O[df] *= cr;           \
    }                                                                         \
    _Pragma("unroll") for (int nf = 0; nf < 4; ++nf) {                        \
      _Pragma("unroll") for (int r = 0; r < 4; ++r)                           \
        S[nf][r] = __builtin_amdgcn_exp2f(S[nf][r] - mm);                     \
    }                                                                         \
    float ps = 0.f, p2 = 0.f;                                                 \
    _Pragma("unroll") for (int nf = 0; nf < 4; ++nf) {                        \
      u32 w0 = pk2h(S[nf][0], S[nf][1]);                                      \
      u32 w1 = pk2h(S[nf][2], S[nf][3]);                                      \
      ACC_PS_P2(w0, ps, p2);                                                  \
      ACC_PS_P2(w1, ps, p2);                                                  \
      int slot = 2 * nf + (g >> 1);                                           \
      u32x2 pk = {w0, w1};                                                    \
      *(u32x2*)(ptw + li * 128 + ((slot * 16) ^ swz) + (g & 1) * 8) = pk;     \
    }                                                                         \
    ll += ps;                                                                 \
    ss2 += p2;                                                                \
  } while (0)

  int cur = 0;
  STAGE(0, 0);
  __syncthreads();
  for (int kc = 0; kc < 16; ++kc) {
    if (kc < 15) STAGE(cur ^ 1, (kc + 1) * 64);
    const char* kb = (const char*)&kbuf[cur][0][0];
    const char* vb = (const char*)&kbuf[cur][1][0];
    f32x4 S0[4] = {zz, zz, zz, zz};
    f32x4 S1[4] = {zz, zz, zz, zz};
    __builtin_amdgcn_s_setprio(1);
#pragma unroll
    for (int ks = 0; ks < 2; ++ks) {
#pragma unroll
      for (int nf = 0; nf < 4; ++nf) {
        int off = (16 * nf + li) * 128 + (((4 * ks + g) * 16) ^ swz);
        u16x8 kh = *(const u16x8*)(kb + off);
        S0[nf] = mfma16h(kh, qb_h[0][ks], S0[nf]);
        S1[nf] = mfma16h(kh, qb_h[1][ks], S1[nf]);
      }
    }
    __builtin_amdgcn_s_setprio(0);
    SOFT(S0, m0, l0, s20, O0);
    u16x8 pb0[2];
    pb0[0] = *(const u16x8*)(ptw + li * 128 + ((g * 16) ^ swz));
    pb0[1] = *(const u16x8*)(ptw + li * 128 + (((4 + g) * 16) ^ swz));
    SOFT(S1, m1, l1, s21, O1);
    u16x8 pb1[2];
    pb1[0] = *(const u16x8*)(ptw + li * 128 + ((g * 16) ^ swz));
    pb1[1] = *(const u16x8*)(ptw + li * 128 + (((4 + g) * 16) ^ swz));
    __builtin_amdgcn_s_setprio(1);
#pragma unroll
    for (int ks = 0; ks < 2; ++ks) {
#pragma unroll
      for (int df = 0; df < 4; ++df) {
        u16x8 va = *(const u16x8*)(vb + (16 * df + li) * 128 + (((4 * ks + g) * 16) ^ swz));
        O0[df] = mfma16h(va, pb0[ks], O0[df]);
        O1[df] = mfma16h(va, pb1[ks], O1[df]);
      }
    }
    __builtin_amdgcn_s_setprio(0);
    __syncthreads();
    cur ^= 1;
  }

  float wacc = 0.f;
  l0 += __shfl_xor(l0, 16, 64);
  l0 += __shfl_xor(l0, 32, 64);
  s20 += __shfl_xor(s20, 16, 64);
  s20 += __shfl_xor(s20, 32, 64);
  l1 += __shfl_xor(l1, 16, 64);
  l1 += __shfl_xor(l1, 32, 64);
  s21 += __shfl_xor(s21, 16, 64);
  s21 += __shfl_xor(s21, 32, 64);
  float il0 = 1.0f / l0, il1 = 1.0f / l1;
#pragma unroll
  for (int df = 0; df < 4; ++df) {
    O0[df] *= il0;
    O1[df] *= il1;
  }
  {
    float s2w = s20 * il0 * il0;
    s2w += __shfl_xor(s2w, 1, 64);
    s2w += __shfl_xor(s2w, 2, 64);
    s2w += __shfl_xor(s2w, 4, 64);
    s2w += __shfl_xor(s2w, 8, 64);
    wacc += s2w;
    float s2w1 = s21 * il1 * il1;
    s2w1 += __shfl_xor(s2w1, 1, 64);
    s2w1 += __shfl_xor(s2w1, 2, 64);
    s2w1 += __shfl_xor(s2w1, 4, 64);
    s2w1 += __shfl_xor(s2w1, 8, 64);
    wacc += s2w1;
  }
  if (lane == 0) wvar[w] = wacc;

  float* bounce = (float*)smem;  // [64 e][132] f32 = 33792B
#pragma unroll
  for (int s = 0; s < 2; ++s) {
    const int jg0 = quarter * 256 + s * 128;
    __syncthreads();
#pragma unroll
    for (int df = 0; df < 4; ++df)
#pragma unroll
      for (int r = 0; r < 4; ++r)
        bounce[(df * 16 + g * 4 + r) * 132 + 16 * w + li] = s ? O1[df][r] : O0[df][r];
    __syncthreads();
#pragma unroll
    for (int p = 0; p < 4; ++p) {
      int idx = p * 512 + t;
      int e = idx >> 5, ch = idx & 31;
      f32x4 v = *(const f32x4*)&bounce[e * 132 + ch * 4];
      *(f32x4*)&pout[((size_t)b * 512 + h * 64 + e) * 1024 + jg0 + ch * 4] = v;
    }
  }
  __syncthreads();
  if (t == 0) {
    float s = 0.f;
#pragma unroll
    for (int i = 0; i < 8; ++i) s += wvar[i];
    sump2_g[bid] = s;
  }
#undef STAGE
#undef SOFT
}

// ---------------- K3a: per-bh constants
__global__ __launch_bounds__(64) void k_cvec(
    const float* __restrict__ qpart, const float* __restrict__ sump2_g,
    const float* __restrict__ Wlin, const float* __restrict__ blin,
    float* __restrict__ cvec_g, float* __restrict__ isv_g) {
  const int bh = blockIdx.x, t = threadIdx.x;
  __shared__ float qs[64];
  float s = 0.f;
#pragma unroll
  for (int on = 0; on < 16; ++on) s += qpart[(size_t)bh * 1024 + on * 64 + t];
  qs[t] = s;
  __syncthreads();
  const float MU = 1.0f / 1024.0f;
  float sp2 = sump2_g[bh] + sump2_g[bh + 256] + sump2_g[bh + 512] + sump2_g[bh + 768];
  float var = sp2 * (1.0f / 1048576.0f) - MU * MU;
  float isv = 1.0f / sqrtf(var + EPS);
  float wq = 0.f;
  for (int d = 0; d < 64; ++d) wq += Wlin[t * 64 + d] * qs[d];
  cvec_g[bh * 64 + t] = blin[t] - isv * MU * wq;
  if (t == 0) isv_g[bh] = isv;
}

// ---------------- K3b: out = isv * P_out + cvec[e] + x
__global__ __launch_bounds__(256) void k_fin(
    float* __restrict__ out, const float* __restrict__ x,
    const float* __restrict__ cvec_g, const float* __restrict__ isv_g) {
  const int bid = blockIdx.x, t = threadIdx.x;
  const int bh = bid >> 3, part = bid & 7;
  const float isv = isv_g[bh];
  const size_t base = (size_t)bh * 65536 + part * 8192;
#pragma unroll
  for (int it = 0; it < 8; ++it) {
    size_t off = base + it * 1024 + t * 4;
    float cv = cvec_g[bh * 64 + part * 8 + it];
    f32x4 po = *(const f32x4*)(out + off);
    f32x4 xv = *(const f32x4*)(x + off);
    f32x4 res;
#pragma unroll
    for (int k = 0; k < 4; ++k) res[k] = isv * po[k] + cv + xv[k];
    *(f32x4*)(out + off) = res;
  }
}

extern "C" void kernel_launch(void* const* d_in, const int* in_sizes, int n_in,
                              void* d_out, int out_size, void* d_ws, size_t ws_size,
                              hipStream_t stream) {
  const float* x = (const float*)d_in[0];
  const float* Ws = (const float*)d_in[1];
  const float* bs = (const float*)d_in[2];
  const float* rh = (const float*)d_in[3];
  const float* rw = (const float*)d_in[4];
  const float* Wl = (const float*)d_in[5];
  const float* bl = (const float*)d_in[6];
  char* wsb = (char*)d_ws;
  u16* qh = (u16*)wsb;                               // 32 MiB  q f16, n-major [bh][n][d]
  u16* vw = (u16*)(wsb + (size_t)67108864);          // 32 MiB  Vw f16, d-major [bh][e][n]
  float* pos_t = (float*)(wsb + (size_t)100663296);  //  2 MiB  pos [h][n][d]
  float* qpart = (float*)(wsb + (size_t)102760448);  //  1 MiB  qsum partials
  float* s2g = (float*)(wsb + (size_t)103809024);    //  4 KiB
  float* cvec = (float*)(wsb + (size_t)103813120);   // 64 KiB
  float* isvg = (float*)(wsb + (size_t)103878656);   //  1 KiB
  u16* wsh = (u16*)(wsb + (size_t)103880704);        // 512 KiB W_start f16
  float* out = (float*)d_out;

  k_init<<<2304, 256, 0, stream>>>(Ws, wsh, rh, rw, pos_t);
  k_conv<<<dim3(16, 32), 256, 0, stream>>>(x, wsh, bs, qh, qpart);
  k_vw<<<512, 256, 0, stream>>>(qh, Wl, vw);
  k_attn<<<1024, 512, 0, stream>>>(qh, vw, pos_t, out, s2g);
  k_cvec<<<256, 64, 0, stream>>>(qpart, s2g, Wl, bl, cvec, isvg);
  k_fin<<<2048, 256, 0, stream>>>(out, x, cvec, isvg);
}

// Round 22
// 186.888 us; speedup vs baseline: 2.7820x; 1.0323x over previous
//
#include <hip/hip_runtime.h>

#define EPS 1e-5f

typedef unsigned short u16;
typedef unsigned int u32;
typedef _Float16 f16;
typedef __attribute__((ext_vector_type(8))) u16 u16x8;
typedef __attribute__((ext_vector_type(2))) u32 u32x2;
typedef __attribute__((ext_vector_type(4))) u32 u32x4;
typedef __attribute__((ext_vector_type(8))) f16 f16x8;
typedef __attribute__((ext_vector_type(2))) f16 f16x2;
typedef __attribute__((ext_vector_type(4))) float f32x4;
typedef __attribute__((ext_vector_type(2))) float f32x2;

typedef __attribute__((address_space(3))) u32 lds_u32;
typedef __attribute__((address_space(1))) const u32 gbl_u32;

__device__ __forceinline__ u32 pk2h(float a, float b) {  // f16 pair, elt0 low, RNE
  f32x2 v = {a, b};
  return __builtin_bit_cast(u32, __builtin_convertvector(v, f16x2));
}
__device__ __forceinline__ float h2f(u16 u) {
  return (float)__builtin_bit_cast(f16, u);
}
__device__ __forceinline__ f32x4 mfma16h(u16x8 a, u16x8 b, f32x4 c) {  // f16
  return __builtin_amdgcn_mfma_f32_16x16x32_f16(
      __builtin_bit_cast(f16x8, a), __builtin_bit_cast(f16x8, b), c, 0, 0, 0);
}
__device__ __forceinline__ void gl16(const u16* g, u16* l) {
  __builtin_amdgcn_global_load_lds((gbl_u32*)g, (lds_u32*)l, 16, 0, 0);
}

// ps/p2 accumulation from a packed f16 pair: fdot2 when available, f32 fallback.
#if __has_builtin(__builtin_amdgcn_fdot2)
#define ACC_PS_P2(wrd, ps, p2)                                          \
  do {                                                                  \
    f16x2 _h = __builtin_bit_cast(f16x2, (u32)(wrd));                   \
    f16x2 _one = {(f16)1.0f, (f16)1.0f};                                \
    ps = __builtin_amdgcn_fdot2(_h, _one, ps, false);                   \
    p2 = __builtin_amdgcn_fdot2(_h, _h, p2, false);                     \
  } while (0)
#else
#define ACC_PS_P2(wrd, ps, p2)                                          \
  do {                                                                  \
    float _a = h2f((u16)(wrd)), _b = h2f((u16)((wrd) >> 16));           \
    ps += _a + _b;                                                      \
    p2 = fmaf(_a, _a, fmaf(_b, _b, p2));                                \
  } while (0)
#endif

// ---------------- K_init: W_start -> f16 single plane (blocks 0..255) + pos table
__global__ __launch_bounds__(256) void k_init(
    const float* __restrict__ Ws, u16* __restrict__ wsh,
    const float* __restrict__ rel_h, const float* __restrict__ rel_w,
    float* __restrict__ pos_t) {
  int bid = blockIdx.x;
  if (bid < 256) {
    int i = (bid * 256 + threadIdx.x) * 4;
    f32x4 v = *(const f32x4*)(Ws + i);
    u32 h01 = pk2h(v[0], v[1]), h23 = pk2h(v[2], v[3]);
    u32x2 hh = {h01, h23};
    *(u32x2*)(wsh + i) = hh;
  } else {
    int t = (bid - 256) * 256 + threadIdx.x;  // 524288 exact
    int d = t & 63;
    int n = (t >> 6) & 1023;
    int h = t >> 16;
    int hh = n & 31, ww = n >> 5;
    pos_t[t] = rel_h[(h * 64 + d) * 32 + hh] + rel_w[(h * 64 + d) * 32 + ww];
  }
}

// ---------------- K1: s = W_start @ x + b -> qh (single f16) + qsum partials.
__global__ __launch_bounds__(256, 2) void k_conv(
    const float* __restrict__ x, const u16* __restrict__ wsh,
    const float* __restrict__ bs, u16* __restrict__ qh, float* __restrict__ qpart) {
  __shared__ u16 xt_h[64 * 72];
  __shared__ __align__(16) u16 wbuf[3][4096];  // [buf][64*64] f16, 24KB
  const int on = blockIdx.x, b = blockIdx.y, n0 = on * 64;
  const int t = threadIdx.x, w = t >> 6, lane = t & 63, g = lane >> 4, li = lane & 15;
  const int r8 = lane >> 3, c8 = (lane & 7) ^ r8;
  f32x4 zz = {0.f, 0.f, 0.f, 0.f};
  f32x4 acc[8][4];
#pragma unroll
  for (int ob = 0; ob < 8; ++ob)
#pragma unroll
    for (int i = 0; i < 4; ++i) acc[ob][i] = zz;

#define WSTAGE(buf, ob_, c0_)                                                 \
  do {                                                                        \
    _Pragma("unroll") for (int p = 0; p < 2; ++p) {                           \
      int rq = (ob_) * 64 + 16 * w + 8 * p + r8;                              \
      gl16(wsh + (size_t)rq * 512 + (c0_) + 8 * c8,                           \
           &wbuf[buf][(16 * w + 8 * p) * 64]);                                \
    }                                                                         \
  } while (0)

  for (int kc = 0; kc < 8; ++kc) {
    const int c0 = kc * 64;
    __syncthreads();
    int c = t >> 2, ns = (t & 3) * 16;
    const float* src = x + ((size_t)b * 512 + c0 + c) * 1024 + n0 + ns;
    f32x4 xr[4];
#pragma unroll
    for (int k = 0; k < 4; ++k) xr[k] = *(const f32x4*)(src + 4 * k);
    WSTAGE(0, 0, c0);
    WSTAGE(1, 1, c0);
#pragma unroll
    for (int k = 0; k < 4; ++k)
#pragma unroll
      for (int j = 0; j < 4; ++j) {
        int n = ns + 4 * k + j;
        xt_h[n * 72 + c] = __builtin_bit_cast(u16, (f16)xr[k][j]);
      }
    __syncthreads();  // xt visible; W bufs 0,1 + x drained by barrier
    u16x8 bx[2][4];
#pragma unroll
    for (int ks = 0; ks < 2; ++ks)
#pragma unroll
      for (int nf = 0; nf < 4; ++nf)
        bx[ks][nf] = *(const u16x8*)&xt_h[(16 * nf + li) * 72 + g * 8 + 32 * ks];
#pragma unroll
    for (int ob = 0; ob < 8; ++ob) {
      // Full drain: robust to ANY unaccounted VMEM ops (hoisted loads, spills).
      asm volatile("s_waitcnt vmcnt(0)" ::: "memory");
      const char* wb = (const char*)&wbuf[ob % 3][0];
      u16x8 ah[2];
#pragma unroll
      for (int ks = 0; ks < 2; ++ks) {
        int off = (16 * w + li) * 128 + (((4 * ks + g) * 16) ^ ((li & 7) << 4));
        ah[ks] = *(const u16x8*)(wb + off);
      }
      if (ob < 6) WSTAGE((ob + 2) % 3, ob + 2, c0);
#pragma unroll
      for (int ks = 0; ks < 2; ++ks)
#pragma unroll
        for (int nf = 0; nf < 4; ++nf)
          acc[ob][nf] = mfma16h(ah[ks], bx[ks][nf], acc[ob][nf]);
    }
  }
#undef WSTAGE
  // ---- epilogue: bias, q stores as single f16, qsum partials
#pragma unroll
  for (int ob = 0; ob < 8; ++ob) {
    const int o0 = ob * 64, bh = b * 8 + ob;
    float bias[4];
#pragma unroll
    for (int r = 0; r < 4; ++r) bias[r] = bs[o0 + 16 * w + g * 4 + r];
    float vq[4] = {0.f, 0.f, 0.f, 0.f};
#pragma unroll
    for (int nf = 0; nf < 4; ++nf) {
      float v0 = acc[ob][nf][0] + bias[0], v1 = acc[ob][nf][1] + bias[1];
      float v2 = acc[ob][nf][2] + bias[2], v3 = acc[ob][nf][3] + bias[3];
      vq[0] += v0; vq[1] += v1; vq[2] += v2; vq[3] += v3;
      u32 h01 = pk2h(v0, v1), h23 = pk2h(v2, v3);
      size_t base = ((size_t)bh * 1024 + n0 + 16 * nf + li) * 64 + 16 * w + g * 4;
      u32x2 ph = {h01, h23};
      *(u32x2*)(qh + base) = ph;
    }
#pragma unroll
    for (int r = 0; r < 4; ++r) {
      float s = vq[r];
      s += __shfl_xor(s, 1, 64);
      s += __shfl_xor(s, 2, 64);
      s += __shfl_xor(s, 4, 64);
      s += __shfl_xor(s, 8, 64);
      if (li == 0) qpart[((size_t)bh * 16 + on) * 64 + 16 * w + 4 * g + r] = s;
    }
  }
}

// ---------------- K_vw: Vw = W_lin @ q per (bh, n-half); single-term f16.
__global__ __launch_bounds__(256) void k_vw(
    const u16* __restrict__ qh, const float* __restrict__ Wlin, u16* __restrict__ vw) {
  __shared__ __align__(16) u16 qbuf[2][4096];  // [buf][64n x 64d] 16KB
  __shared__ u16 lw_h[64 * 72];
  __shared__ u16 bounce[64 * 72];
  const int bh = blockIdx.x >> 1, half = blockIdx.x & 1;
  const int t = threadIdx.x, w = t >> 6, lane = t & 63, g = lane >> 4, li = lane & 15;
  const int r8 = lane >> 3, c8 = (lane & 7) ^ r8;
  const u16* qhb = qh + (size_t)bh * 65536;
  f32x4 zz = {0.f, 0.f, 0.f, 0.f};

  {  // stage W_lin (single f16)
    int e = t >> 2, ds = (t & 3) * 16;
    const float* src = Wlin + e * 64 + ds;
    float arr[16];
#pragma unroll
    for (int k = 0; k < 4; ++k) *(f32x4*)&arr[4 * k] = *(const f32x4*)(src + 4 * k);
#pragma unroll
    for (int p = 0; p < 8; ++p)
      *(u32*)&lw_h[e * 72 + ds + 2 * p] = pk2h(arr[2 * p], arr[2 * p + 1]);
  }
#define STAGE_Q(bb, n0_)                                                      \
  do {                                                                        \
    _Pragma("unroll") for (int p = 0; p < 2; ++p) {                           \
      int rq = (n0_) + 8 * (w + 4 * p) + r8;                                  \
      gl16(qhb + (size_t)rq * 64 + 8 * c8, &qbuf[bb][(8 * (w + 4 * p)) * 64]); \
    }                                                                         \
  } while (0)

  const int nt0 = half * 8;
  STAGE_Q(0, nt0 * 64);
  __syncthreads();
  u16x8 la_h[2];
#pragma unroll
  for (int ks = 0; ks < 2; ++ks)
    la_h[ks] = *(const u16x8*)&lw_h[(16 * w + li) * 72 + g * 8 + 32 * ks];
  int cur = 0;
  for (int it = 0; it < 8; ++it) {
    const int nt = nt0 + it;
    if (it < 7) STAGE_Q(cur ^ 1, (nt + 1) * 64);
    f32x4 acc2[4] = {zz, zz, zz, zz};
    const char* qb0 = (const char*)&qbuf[cur][0];
#pragma unroll
    for (int ks = 0; ks < 2; ++ks)
#pragma unroll
      for (int nf = 0; nf < 4; ++nf) {
        int off = (16 * nf + li) * 128 + (((4 * ks + g) * 16) ^ ((li & 7) << 4));
        u16x8 qv = *(const u16x8*)(qb0 + off);
        acc2[nf] = mfma16h(la_h[ks], qv, acc2[nf]);
      }
    __syncthreads();
#pragma unroll
    for (int nf = 0; nf < 4; ++nf)
#pragma unroll
      for (int r = 0; r < 4; ++r)
        bounce[(16 * w + 4 * g + r) * 72 + 16 * nf + li] =
            __builtin_bit_cast(u16, (f16)acc2[nf][r]);
    __syncthreads();
    {  // coalesced Vw store: [bh][e][n]
      int e = t >> 2, nc = (t & 3) * 16;
      u16x8 v0 = *(const u16x8*)&bounce[e * 72 + nc];
      u16x8 v1 = *(const u16x8*)&bounce[e * 72 + nc + 8];
      size_t base = ((size_t)bh * 64 + e) * 1024 + nt * 64 + nc;
      *(u16x8*)(vw + base) = v0;
      *(u16x8*)(vw + base + 8) = v1;
    }
    cur ^= 1;
  }
#undef STAGE_Q
}

// ---------------- K2: flash attention; pout stored as f16 (workspace).
__global__ __launch_bounds__(512, 4) void k_attn(
    const u16* __restrict__ qh, const u16* __restrict__ vw,
    const float* __restrict__ pos_t, u16* __restrict__ pout, float* __restrict__ sump2_g) {
  __shared__ __align__(16) char smem[49184];  // kbuf 32K | ptw 8x2K | wvar 32B
  u16(*kbuf)[2][4096] = (u16(*)[2][4096])smem;  // [buf][{kh,vw}][64*64]
  float* wvar = (float*)(smem + 49152);
  const int bid = blockIdx.x, bh = bid & 255, quarter = bid >> 8;
  const int b = bh >> 3, h = bh & 7;
  const int t = threadIdx.x, w = t >> 6, lane = t & 63, g = lane >> 4, li = lane & 15;
  char* ptw = smem + 32768 + w * 2048;
  const u16* qhb = qh + (size_t)bh * 65536;
  const u16* vwb = vw + (size_t)bh * 65536;
  const float* posb = pos_t + (size_t)h * 65536;
  const float SIL = 0.088388347648318447f * 1.4426950408889634f;
  const float L2E = 1.4426950408889634f;
  const int swz = (li & 7) << 4;
  f32x4 zz = {0.f, 0.f, 0.f, 0.f};

  u16x8 qb_h[2][2];
  const int jr0 = quarter * 256 + 16 * w;
#pragma unroll
  for (int s = 0; s < 2; ++s) {
    int jr = jr0 + s * 128 + li;
#pragma unroll
    for (int ks = 0; ks < 2; ++ks) {
      int dc = 32 * ks + 8 * g;
      u16x8 hh = *(const u16x8*)(qhb + (size_t)jr * 64 + dc);
      const float* sp = posb + (size_t)jr * 64 + dc;
      f32x4 p0 = *(const f32x4*)sp, p1 = *(const f32x4*)(sp + 4);
      u32 AW[4];
#pragma unroll
      for (int p = 0; p < 4; ++p) {
        float pa = (2 * p < 4) ? p0[2 * p] : p1[2 * p - 4];
        float pb = (2 * p + 1 < 4) ? p0[2 * p + 1] : p1[2 * p - 3];
        float v0 = h2f(hh[2 * p]) * SIL + pa * L2E;
        float v1 = h2f(hh[2 * p + 1]) * SIL + pb * L2E;
        AW[p] = pk2h(v0, v1);
      }
      u32x4 av = {AW[0], AW[1], AW[2], AW[3]};
      qb_h[s][ks] = __builtin_bit_cast(u16x8, av);
    }
  }

#define STAGE(bb, k0)                                                         \
  do {                                                                        \
    int r8 = lane >> 3, c8 = (lane & 7) ^ r8;                                 \
    int rq = (k0) + 8 * w + r8;                                               \
    gl16(qhb + (size_t)rq * 64 + 8 * c8, &kbuf[bb][0][w * 512]);              \
    gl16(vwb + (size_t)(8 * w + r8) * 1024 + (k0) + 8 * c8,                   \
         &kbuf[bb][1][w * 512]);                                              \
  } while (0)

  float m0 = -3.0e38f, l0 = 0.f, s20 = 0.f;
  float m1 = -3.0e38f, l1 = 0.f, s21 = 0.f;
  f32x4 O0[4], O1[4];
#pragma unroll
  for (int df = 0; df < 4; ++df) {
    O0[df] = zz;
    O1[df] = zz;
  }

#define SOFT(S, mm, ll, ss2, O)                                               \
  do {                                                                        \
    float t0 = fmaxf(fmaxf(S[0][0], S[0][1]), fmaxf(S[0][2], S[0][3]));       \
    float t1 = fmaxf(fmaxf(S[1][0], S[1][1]), fmaxf(S[1][2], S[1][3]));       \
    float t2 = fmaxf(fmaxf(S[2][0], S[2][1]), fmaxf(S[2][2], S[2][3]));       \
    float t3 = fmaxf(fmaxf(S[3][0], S[3][1]), fmaxf(S[3][2], S[3][3]));       \
    float tl = fmaxf(fmaxf(t0, t1), fmaxf(t2, t3));                           \
    if (__any(tl > mm + 12.f)) {                                              \
      float tm = fmaxf(tl, __shfl_xor(tl, 16, 64));                           \
      tm = fmaxf(tm, __shfl_xor(tm, 32, 64));                                 \
      float mn = fmaxf(mm, tm);                                               \
      float cr = __builtin_amdgcn_exp2f(mm - mn);                             \
      mm = mn;                                                                \
      ll *= cr;                                                               \
      ss2 *= cr * cr;                                                         \
      _Pragma("unroll") for (int df = 0; df < 4; ++df) O[df] *= cr;           \
    }                                                                         \
    _Pragma("unroll") for (int nf = 0; nf < 4; ++nf) {                        \
      _Pragma("unroll") for (int r = 0; r < 4; ++r)                           \
        S[nf][r] = __builtin_amdgcn_exp2f(S[nf][r] - mm);                     \
    }                                                                         \
    float ps = 0.f, p2 = 0.f;                                                 \
    _Pragma("unroll") for (int nf = 0; nf < 4; ++nf) {                        \
      u32 w0 = pk2h(S[nf][0], S[nf][1]);                                      \
      u32 w1 = pk2h(S[nf][2], S[nf][3]);                                      \
      ACC_PS_P2(w0, ps, p2);                                                  \
      ACC_PS_P2(w1, ps, p2);                                                  \
      int slot = 2 * nf + (g >> 1);                                           \
      u32x2 pk = {w0, w1};                                                    \
      *(u32x2*)(ptw + li * 128 + ((slot * 16) ^ swz) + (g & 1) * 8) = pk;     \
    }                                                                         \
    ll += ps;                                                                 \
    ss2 += p2;                                                                \
  } while (0)

  int cur = 0;
  STAGE(0, 0);
  __syncthreads();
  for (int kc = 0; kc < 16; ++kc) {
    if (kc < 15) STAGE(cur ^ 1, (kc + 1) * 64);
    const char* kb = (const char*)&kbuf[cur][0][0];
    const char* vb = (const char*)&kbuf[cur][1][0];
    f32x4 S0[4] = {zz, zz, zz, zz};
    f32x4 S1[4] = {zz, zz, zz, zz};
    __builtin_amdgcn_s_setprio(1);
#pragma unroll
    for (int ks = 0; ks < 2; ++ks) {
#pragma unroll
      for (int nf = 0; nf < 4; ++nf) {
        int off = (16 * nf + li) * 128 + (((4 * ks + g) * 16) ^ swz);
        u16x8 kh = *(const u16x8*)(kb + off);
        S0[nf] = mfma16h(kh, qb_h[0][ks], S0[nf]);
        S1[nf] = mfma16h(kh, qb_h[1][ks], S1[nf]);
      }
    }
    __builtin_amdgcn_s_setprio(0);
    SOFT(S0, m0, l0, s20, O0);
    u16x8 pb0[2];
    pb0[0] = *(const u16x8*)(ptw + li * 128 + ((g * 16) ^ swz));
    pb0[1] = *(const u16x8*)(ptw + li * 128 + (((4 + g) * 16) ^ swz));
    SOFT(S1, m1, l1, s21, O1);
    u16x8 pb1[2];
    pb1[0] = *(const u16x8*)(ptw + li * 128 + ((g * 16) ^ swz));
    pb1[1] = *(const u16x8*)(ptw + li * 128 + (((4 + g) * 16) ^ swz));
    __builtin_amdgcn_s_setprio(1);
#pragma unroll
    for (int ks = 0; ks < 2; ++ks) {
#pragma unroll
      for (int df = 0; df < 4; ++df) {
        u16x8 va = *(const u16x8*)(vb + (16 * df + li) * 128 + (((4 * ks + g) * 16) ^ swz));
        O0[df] = mfma16h(va, pb0[ks], O0[df]);
        O1[df] = mfma16h(va, pb1[ks], O1[df]);
      }
    }
    __builtin_amdgcn_s_setprio(0);
    __syncthreads();
    cur ^= 1;
  }

  float wacc = 0.f;
  l0 += __shfl_xor(l0, 16, 64);
  l0 += __shfl_xor(l0, 32, 64);
  s20 += __shfl_xor(s20, 16, 64);
  s20 += __shfl_xor(s20, 32, 64);
  l1 += __shfl_xor(l1, 16, 64);
  l1 += __shfl_xor(l1, 32, 64);
  s21 += __shfl_xor(s21, 16, 64);
  s21 += __shfl_xor(s21, 32, 64);
  float il0 = 1.0f / l0, il1 = 1.0f / l1;
#pragma unroll
  for (int df = 0; df < 4; ++df) {
    O0[df] *= il0;
    O1[df] *= il1;
  }
  {
    float s2w = s20 * il0 * il0;
    s2w += __shfl_xor(s2w, 1, 64);
    s2w += __shfl_xor(s2w, 2, 64);
    s2w += __shfl_xor(s2w, 4, 64);
    s2w += __shfl_xor(s2w, 8, 64);
    wacc += s2w;
    float s2w1 = s21 * il1 * il1;
    s2w1 += __shfl_xor(s2w1, 1, 64);
    s2w1 += __shfl_xor(s2w1, 2, 64);
    s2w1 += __shfl_xor(s2w1, 4, 64);
    s2w1 += __shfl_xor(s2w1, 8, 64);
    wacc += s2w1;
  }
  if (lane == 0) wvar[w] = wacc;

  // ---- write both sets via f16 LDS bounce, coalesced u16x8 stores
  u16* bounce = (u16*)smem;  // [64 e][136] u16 = 17408B
#pragma unroll
  for (int s = 0; s < 2; ++s) {
    const int jg0 = quarter * 256 + s * 128;
    __syncthreads();
#pragma unroll
    for (int df = 0; df < 4; ++df)
#pragma unroll
      for (int r = 0; r < 4; ++r)
        bounce[(df * 16 + g * 4 + r) * 136 + 16 * w + li] =
            __builtin_bit_cast(u16, (f16)(s ? O1[df][r] : O0[df][r]));
    __syncthreads();
#pragma unroll
    for (int p = 0; p < 2; ++p) {
      int idx = p * 512 + t;
      int e = idx >> 4, ch = idx & 15;
      u16x8 v = *(const u16x8*)&bounce[e * 136 + ch * 8];
      *(u16x8*)&pout[((size_t)b * 512 + h * 64 + e) * 1024 + jg0 + ch * 8] = v;
    }
  }
  __syncthreads();
  if (t == 0) {
    float s = 0.f;
#pragma unroll
    for (int i = 0; i < 8; ++i) s += wvar[i];
    sump2_g[bid] = s;
  }
#undef STAGE
#undef SOFT
}

// ---------------- K3a: per-bh constants
__global__ __launch_bounds__(64) void k_cvec(
    const float* __restrict__ qpart, const float* __restrict__ sump2_g,
    const float* __restrict__ Wlin, const float* __restrict__ blin,
    float* __restrict__ cvec_g, float* __restrict__ isv_g) {
  const int bh = blockIdx.x, t = threadIdx.x;
  __shared__ float qs[64];
  float s = 0.f;
#pragma unroll
  for (int on = 0; on < 16; ++on) s += qpart[(size_t)bh * 1024 + on * 64 + t];
  qs[t] = s;
  __syncthreads();
  const float MU = 1.0f / 1024.0f;
  float sp2 = sump2_g[bh] + sump2_g[bh + 256] + sump2_g[bh + 512] + sump2_g[bh + 768];
  float var = sp2 * (1.0f / 1048576.0f) - MU * MU;
  float isv = 1.0f / sqrtf(var + EPS);
  float wq = 0.f;
  for (int d = 0; d < 64; ++d) wq += Wlin[t * 64 + d] * qs[d];
  cvec_g[bh * 64 + t] = blin[t] - isv * MU * wq;
  if (t == 0) isv_g[bh] = isv;
}

// ---------------- K3b: out = isv * pout(f16) + cvec[e] + x
__global__ __launch_bounds__(256) void k_fin(
    float* __restrict__ out, const float* __restrict__ x, const u16* __restrict__ pout,
    const float* __restrict__ cvec_g, const float* __restrict__ isv_g) {
  const int bid = blockIdx.x, t = threadIdx.x;
  const int bh = bid >> 3, part = bid & 7;
  const float isv = isv_g[bh];
  const size_t base = (size_t)bh * 65536 + part * 8192;
#pragma unroll
  for (int it = 0; it < 4; ++it) {
    size_t off = base + it * 2048 + t * 8;
    int e = (part * 8192 + it * 2048 + t * 8) >> 10;
    float cv = cvec_g[bh * 64 + e];
    u16x8 po = *(const u16x8*)(pout + off);
    f32x4 xv0 = *(const f32x4*)(x + off);
    f32x4 xv1 = *(const f32x4*)(x + off + 4);
    f32x4 r0, r1;
#pragma unroll
    for (int k = 0; k < 4; ++k) {
      r0[k] = isv * h2f(po[k]) + cv + xv0[k];
      r1[k] = isv * h2f(po[k + 4]) + cv + xv1[k];
    }
    *(f32x4*)(out + off) = r0;
    *(f32x4*)(out + off + 4) = r1;
  }
}

extern "C" void kernel_launch(void* const* d_in, const int* in_sizes, int n_in,
                              void* d_out, int out_size, void* d_ws, size_t ws_size,
                              hipStream_t stream) {
  const float* x = (const float*)d_in[0];
  const float* Ws = (const float*)d_in[1];
  const float* bs = (const float*)d_in[2];
  const float* rh = (const float*)d_in[3];
  const float* rw = (const float*)d_in[4];
  const float* Wl = (const float*)d_in[5];
  const float* bl = (const float*)d_in[6];
  char* wsb = (char*)d_ws;
  u16* qh = (u16*)wsb;                               // 32 MiB  q f16, n-major [bh][n][d]
  u16* pout = (u16*)(wsb + (size_t)33554432);        // 32 MiB  P_out f16 [b][c][n]
  u16* vw = (u16*)(wsb + (size_t)67108864);          // 32 MiB  Vw f16, d-major [bh][e][n]
  float* pos_t = (float*)(wsb + (size_t)100663296);  //  2 MiB  pos [h][n][d]
  float* qpart = (float*)(wsb + (size_t)102760448);  //  1 MiB  qsum partials
  float* s2g = (float*)(wsb + (size_t)103809024);    //  4 KiB
  float* cvec = (float*)(wsb + (size_t)103813120);   // 64 KiB
  float* isvg = (float*)(wsb + (size_t)103878656);   //  1 KiB
  u16* wsh = (u16*)(wsb + (size_t)103880704);        // 512 KiB W_start f16
  float* out = (float*)d_out;

  k_init<<<2304, 256, 0, stream>>>(Ws, wsh, rh, rw, pos_t);
  k_conv<<<dim3(16, 32), 256, 0, stream>>>(x, wsh, bs, qh, qpart);
  k_vw<<<512, 256, 0, stream>>>(qh, Wl, vw);
  k_attn<<<1024, 512, 0, stream>>>(qh, vw, pos_t, pout, s2g);
  k_cvec<<<256, 64, 0, stream>>>(qpart, s2g, Wl, bl, cvec, isvg);
  k_fin<<<2048, 256, 0, stream>>>(out, x, pout, cvec, isvg);
}